// Round 5
// baseline (407.149 us; speedup 1.0000x reference)
//
#include <hip/hip_runtime.h>
#include <math.h>

// GCN: 2x GraphConv(norm='both') + projection + softmax.
// N=100000 nodes, E=1600000 edges, feats 128 -> 64 -> 64 -> 8. All fp32.
//
// R4 post-mortem: group_kernel was latency-bound at 7.7% occupancy (196 WGs
// of 8192 edges). R5: CHUNK 8192->2048 (782 WGs, ~38% occ), edges cached in
// registers across phases, norm_src folded into local_csr_kernel.

#define NODES   100000
#define INF     128
#define HID     64
#define NLAB    8

#define BSHIFT  7                       // 128 nodes per bucket
#define BNODES  128
#define NB      ((NODES + BNODES - 1) / BNODES)   // 782
#define CAP     2600                    // bucket capacity (mean 2046, ~12 sigma)
#define CHUNK   2048                    // edges per group_kernel WG
#define EPT     (CHUNK / 256)           // 8 edges per thread
#define SRCMASK 131071                  // 17 bits

// ---------------- group: bucket edges by dst>>7, count deg_out ----------------

__global__ void group_kernel(const int* __restrict__ src, const int* __restrict__ dst,
                             int* __restrict__ deg_o, int* __restrict__ gcur,
                             int* __restrict__ packed, int E) {
    __shared__ int hist[NB];
    __shared__ int base[NB];

    const int tid = threadIdx.x;
    const int e0 = blockIdx.x * CHUNK;

    for (int i = tid; i < NB; i += 256) hist[i] = 0;
    __syncthreads();

    // phase 1: histogram + deg_out; cache edges in registers
    int es[EPT], ed[EPT];
#pragma unroll
    for (int i = 0; i < EPT; ++i) {
        int e = e0 + tid + i * 256;
        if (e < E) {
            es[i] = src[e];
            ed[i] = dst[e];
            atomicAdd(&deg_o[es[i]], 1);
            atomicAdd(&hist[ed[i] >> BSHIFT], 1);
        } else es[i] = -1;
    }
    __syncthreads();

    // phase 2: reserve space per bucket (one far atomic per non-empty bucket)
    for (int b = tid; b < NB; b += 256) {
        int c = hist[b];
        base[b] = c ? atomicAdd(&gcur[b], c) : 0;
    }
    __syncthreads();
    for (int b = tid; b < NB; b += 256) hist[b] = 0;   // reuse as running rank
    __syncthreads();

    // phase 3: write packed (dst_local<<17 | src) into contiguous bucket runs
#pragma unroll
    for (int i = 0; i < EPT; ++i) {
        if (es[i] >= 0) {
            int b = ed[i] >> BSHIFT;
            int pos = base[b] + atomicAdd(&hist[b], 1);
            if (pos < CAP)
                packed[(size_t)b * CAP + pos] = ((ed[i] & (BNODES - 1)) << 17) | es[i];
        }
    }
}

// ---------------- per-bucket counting sort -> exact CSR (in place) ----------------
// WG b: stage packed[b] in LDS, histogram 128 local dsts, scan, rank-scatter in
// LDS, write dst-sorted src ids back over packed[b]. Emits starts/ends/norms.

__global__ void local_csr_kernel(int* __restrict__ packed, const int* __restrict__ gcur,
                                 const int* __restrict__ deg_o,
                                 int* __restrict__ starts, int* __restrict__ ends,
                                 float* __restrict__ norm_s, float* __restrict__ norm_d,
                                 int Nn) {
    __shared__ int raw[CAP];
    __shared__ int sorted[CAP];
    __shared__ int hist[BNODES];
    __shared__ int excl[BNODES];

    const int tid = threadIdx.x;
    const int b = blockIdx.x;
    const int cnt = min(gcur[b], CAP);
    int* reg = packed + (size_t)b * CAP;

    for (int i = tid; i < BNODES; i += 256) hist[i] = 0;
    __syncthreads();

    for (int i = tid; i < cnt; i += 256) {
        int pe = reg[i];
        raw[i] = pe;
        atomicAdd(&hist[pe >> 17], 1);
    }
    __syncthreads();

    // exclusive scan of 128 degrees (Hillis-Steele, first 128 threads)
    if (tid < BNODES) excl[tid] = hist[tid];
    __syncthreads();
    for (int off = 1; off < BNODES; off <<= 1) {
        int v = 0;
        if (tid < BNODES && tid >= off) v = excl[tid - off];
        __syncthreads();
        if (tid < BNODES) excl[tid] += v;
        __syncthreads();
    }
    if (tid < BNODES) {
        int deg = hist[tid];
        int st = excl[tid] - deg;               // exclusive
        int node = b * BNODES + tid;
        if (node < Nn) {
            int gs = b * CAP + st;
            starts[node] = gs;
            ends[node]   = gs + deg;
            norm_d[node] = rsqrtf(fmaxf((float)deg, 1.0f));
            norm_s[node] = rsqrtf(fmaxf((float)deg_o[node], 1.0f));
        }
        hist[tid] = st;                          // reuse as cursor
    }
    __syncthreads();

    // rank scatter into sorted[]
    for (int i = tid; i < cnt; i += 256) {
        int pe = raw[i];
        int pos = atomicAdd(&hist[pe >> 17], 1);
        sorted[pos] = pe & SRCMASK;
    }
    __syncthreads();

    // coalesced write-back over the packed region
    for (int i = tid; i < cnt; i += 256) reg[i] = sorted[i];
}

// ---------------- GEMM: H[row,:] = norm[row] * (X[row,:] @ W) ----------------

template <int K>
__global__ void gemm_norm_kernel(const float* __restrict__ X, const float* __restrict__ norm,
                                 const float* __restrict__ W, float* __restrict__ H, int M) {
    constexpr int KS = K + 4;
    __shared__ float sW[K * 64];
    __shared__ float sX[16 * KS];

    const int tid = threadIdx.x;
    const int row0 = blockIdx.x * 16;

    for (int i = tid; i < K * 16; i += 256)
        ((float4*)sW)[i] = ((const float4*)W)[i];
    for (int i = tid; i < 4 * K; i += 256) {
        int eo = i * 4;
        int r = eo / K, k = eo % K;
        int gr = row0 + r;
        float4 v = (gr < M) ? ((const float4*)(X + (size_t)gr * K))[k >> 2]
                            : make_float4(0.f, 0.f, 0.f, 0.f);
        ((float4*)(sX + r * KS))[k >> 2] = v;
    }
    __syncthreads();

    const int c4 = tid & 15;
    const int r  = tid >> 4;
    const int grow = row0 + r;
    const float* xr = sX + r * KS;

    float4 acc = make_float4(0.f, 0.f, 0.f, 0.f);
#pragma unroll 8
    for (int k = 0; k < K; ++k) {
        float xv = xr[k];
        float4 w = ((const float4*)(sW + k * 64))[c4];
        acc.x = fmaf(xv, w.x, acc.x);
        acc.y = fmaf(xv, w.y, acc.y);
        acc.z = fmaf(xv, w.z, acc.z);
        acc.w = fmaf(xv, w.w, acc.w);
    }
    if (grow < M) {
        float nm = norm[grow];
        acc.x *= nm; acc.y *= nm; acc.z *= nm; acc.w *= nm;
        ((float4*)(H + (size_t)grow * 64))[c4] = acc;
    }
}

// ---------------- pull gather + fused epilogue ----------------
// One wave per dst node. Quarter q handles edges i = start+q, start+q+4, ...;
// lane-in-quarter c reads float4 cols 4c..4c+3. Cross-quarter shfl reduce.
// X[n,:] = relu(norm_d[n] * sum_{s in csr(n)} H[s,:] + b)

__global__ void gather_kernel(const int* __restrict__ starts, const int* __restrict__ ends,
                              const int* __restrict__ csr, const float* __restrict__ H,
                              const float* __restrict__ nd, const float* __restrict__ b,
                              float* __restrict__ X, int Nn) {
    int node = blockIdx.x * 4 + (threadIdx.x >> 6);
    if (node >= Nn) return;                     // wave-uniform
    int lane = threadIdx.x & 63;
    int q = lane >> 4, c = lane & 15;

    int start = starts[node], end = ends[node];
    float4 acc = make_float4(0.f, 0.f, 0.f, 0.f);
    for (int i = start + q; i < end; i += 4) {
        int s = csr[i];
        float4 v = ((const float4*)(H + (size_t)s * 64))[c];
        acc.x += v.x; acc.y += v.y; acc.z += v.z; acc.w += v.w;
    }
#pragma unroll
    for (int m = 16; m <= 32; m <<= 1) {
        acc.x += __shfl_xor(acc.x, m, 64);
        acc.y += __shfl_xor(acc.y, m, 64);
        acc.z += __shfl_xor(acc.z, m, 64);
        acc.w += __shfl_xor(acc.w, m, 64);
    }
    if (q == 0) {
        float nm = nd[node];
        float4 bb = ((const float4*)b)[c];
        float4 r;
        r.x = fmaxf(fmaf(acc.x, nm, bb.x), 0.f);
        r.y = fmaxf(fmaf(acc.y, nm, bb.y), 0.f);
        r.z = fmaxf(fmaf(acc.z, nm, bb.z), 0.f);
        r.w = fmaxf(fmaf(acc.w, nm, bb.w), 0.f);
        ((float4*)(X + (size_t)node * 64))[c] = r;
    }
}

// ---------------- projection (64x8) + softmax ----------------

__global__ void proj_softmax_kernel(const float* __restrict__ X, const float* __restrict__ Wp,
                                    const float* __restrict__ bp, float* __restrict__ out, int M) {
    __shared__ float sW[64 * NLAB];
    __shared__ float sb[NLAB];
    int tid = threadIdx.x;
    for (int i = tid; i < 64 * NLAB; i += 256) sW[i] = Wp[i];
    if (tid < NLAB) sb[tid] = bp[tid];
    __syncthreads();

    int row = blockIdx.x * 256 + tid;
    if (row >= M) return;

    float logit[NLAB];
#pragma unroll
    for (int l = 0; l < NLAB; ++l) logit[l] = sb[l];
    const float4* x4 = (const float4*)(X + (size_t)row * 64);
#pragma unroll 4
    for (int kk = 0; kk < 16; ++kk) {
        float4 v = x4[kk];
        const float xs[4] = {v.x, v.y, v.z, v.w};
#pragma unroll
        for (int j = 0; j < 4; ++j) {
            int k = kk * 4 + j;
            float xv = xs[j];
#pragma unroll
            for (int l = 0; l < NLAB; ++l)
                logit[l] = fmaf(xv, sW[k * NLAB + l], logit[l]);
        }
    }
    float mx = logit[0];
#pragma unroll
    for (int l = 1; l < NLAB; ++l) mx = fmaxf(mx, logit[l]);
    float s = 0.0f;
#pragma unroll
    for (int l = 0; l < NLAB; ++l) { logit[l] = __expf(logit[l] - mx); s += logit[l]; }
    float inv = 1.0f / s;
#pragma unroll
    for (int l = 0; l < NLAB; ++l) out[(size_t)row * NLAB + l] = logit[l] * inv;
}

// ---------------- launch ----------------

extern "C" void kernel_launch(void* const* d_in, const int* in_sizes, int n_in,
                              void* d_out, int out_size, void* d_ws, size_t ws_size,
                              hipStream_t stream) {
    const float* features = (const float*)d_in[0];
    const int*   edge_src = (const int*)d_in[1];
    const int*   edge_dst = (const int*)d_in[2];
    const float* W1 = (const float*)d_in[4];
    const float* b1 = (const float*)d_in[5];
    const float* W2 = (const float*)d_in[6];
    const float* b2 = (const float*)d_in[7];
    const float* Wp = (const float*)d_in[8];
    const float* bp = (const float*)d_in[9];
    float* out = (float*)d_out;

    const int N = NODES;
    const int E = in_sizes[1];

    // ---- workspace layout (~62 MB) ----
    char* p = (char*)d_ws;
    int*   deg_o  = (int*)p;            p += sizeof(int) * N;          // zeroed
    int*   gcur   = (int*)p;            p += sizeof(int) * NB;         // zeroed
    int*   packed = (int*)p;            p += sizeof(int) * (size_t)NB * CAP;  // -> csr
    int*   starts = (int*)p;            p += sizeof(int) * N;
    int*   ends   = (int*)p;            p += sizeof(int) * N;
    float* norm_s = (float*)p;          p += sizeof(float) * N;
    float* norm_d = (float*)p;          p += sizeof(float) * N;
    p = (char*)(((size_t)p + 255) & ~(size_t)255);
    float* h      = (float*)p;          p += sizeof(float) * (size_t)N * 64;
    float* x      = (float*)p;          p += sizeof(float) * (size_t)N * 64;

    hipMemsetAsync(deg_o, 0, sizeof(int) * ((size_t)N + NB), stream);  // deg_o + gcur

    // ---- CSR build: coarse bucket + in-LDS counting sort ----
    group_kernel<<<(E + CHUNK - 1) / CHUNK, 256, 0, stream>>>(edge_src, edge_dst,
                                                              deg_o, gcur, packed, E);
    local_csr_kernel<<<NB, 256, 0, stream>>>(packed, gcur, deg_o, starts, ends,
                                             norm_s, norm_d, N);

    // ---- layer 1 ----
    gemm_norm_kernel<INF><<<(N + 15) / 16, 256, 0, stream>>>(features, norm_s, W1, h, N);
    gather_kernel<<<(N + 3) / 4, 256, 0, stream>>>(starts, ends, packed, h, norm_d, b1, x, N);

    // ---- layer 2 ----
    gemm_norm_kernel<HID><<<(N + 15) / 16, 256, 0, stream>>>(x, norm_s, W2, h, N);
    gather_kernel<<<(N + 3) / 4, 256, 0, stream>>>(starts, ends, packed, h, norm_d, b2, x, N);

    // ---- projection + softmax ----
    proj_softmax_kernel<<<(N + 255) / 256, 256, 0, stream>>>(x, Wp, bp, out, N);
}

// Round 6
// 373.332 us; speedup vs baseline: 1.0906x; 1.0906x over previous
//
#include <hip/hip_runtime.h>
#include <math.h>

// GCN: 2x GraphConv(norm='both') + projection + softmax.
// N=100000 nodes, E=1600000 edges, feats 128 -> 64 -> 64 -> 8. All fp32.
//
// R5 post-mortem: group_kernel pinned at ~90 us regardless of occupancy ->
// the wall is random-LINE global atomic RMW (~18.5k lines/us device-wide;
// 1.6M deg_o atomics = 86 us, matching). R6: zero random global atomics.
// Radix partition by dst>>9 (+ src>>9 for degrees) with per-bucket hot-line
// reservations only; per-half-bucket LDS counting sort -> exact CSR; src
// degree histogram per bucket -> norm_s. Gather (R1 design) unchanged.

#define NODES   100000
#define INF     128
#define HID     64
#define NLAB    8

#define SB      512                         // nodes per super-bucket
#define NSB     ((NODES + SB - 1) / SB)     // 196
#define NHALF   ((NODES + 255) / 256)       // 391 half-buckets (256 nodes)
#define CAP1    9000                        // per-sb edge cap (mean 8192, sigma~90)
#define SCAP    9000                        // per-sb src cap
#define CAP2    4600                        // per-half edge cap (mean 4096, sigma~64)
#define PCHUNK  4096                        // edges per part WG
#define PEPT    (PCHUNK / 256)              // 16
#define SRCMASK 0x1FFFF                     // 17 bits

// ---------------- partition edges by dst>>9; src vals by src>>9 ----------------

__global__ void part_kernel(const int* __restrict__ src, const int* __restrict__ dst,
                            int* __restrict__ gcur_d, int* __restrict__ gcur_s,
                            int* __restrict__ dreg, unsigned short* __restrict__ sreg, int E) {
    __shared__ int hd[NSB], hs[NSB], bd[NSB], bs[NSB];
    const int tid = threadIdx.x;
    const int e0 = blockIdx.x * PCHUNK;

    for (int i = tid; i < NSB; i += 256) { hd[i] = 0; hs[i] = 0; }
    __syncthreads();

    // phase A: LDS histograms; cache edges in registers
    int es[PEPT], ed[PEPT];
#pragma unroll
    for (int i = 0; i < PEPT; ++i) {
        int e = e0 + tid + i * 256;
        if (e < E) {
            es[i] = src[e]; ed[i] = dst[e];
            atomicAdd(&hd[ed[i] >> 9], 1);
            atomicAdd(&hs[es[i] >> 9], 1);
        } else es[i] = -1;
    }
    __syncthreads();

    // phase B: reserve contiguous runs (hot-line far atomics only: 392 addrs)
    for (int b = tid; b < NSB; b += 256) {
        int c = hd[b]; bd[b] = c ? atomicAdd(&gcur_d[b], c) : 0;
        c = hs[b];     bs[b] = c ? atomicAdd(&gcur_s[b], c) : 0;
    }
    __syncthreads();
    for (int b = tid; b < NSB; b += 256) { hd[b] = 0; hs[b] = 0; }
    __syncthreads();

    // phase C: scatter into runs (dst_local<<17 | src; src_local as ushort)
#pragma unroll
    for (int i = 0; i < PEPT; ++i) {
        if (es[i] >= 0) {
            int s = es[i], d = ed[i];
            int kb = d >> 9;
            int pos = bd[kb] + atomicAdd(&hd[kb], 1);
            if (pos < CAP1) dreg[(size_t)kb * CAP1 + pos] = ((d & (SB - 1)) << 17) | s;
            int ks = s >> 9;
            int ps = bs[ks] + atomicAdd(&hs[ks], 1);
            if (ps < SCAP) sreg[(size_t)ks * SCAP + ps] = (unsigned short)(s & (SB - 1));
        }
    }
}

// ---------------- src-degree histogram per super-bucket -> norm_s ----------------

__global__ void shist_kernel(const unsigned short* __restrict__ sreg,
                             const int* __restrict__ gcur_s,
                             float* __restrict__ norm_s, int Nn) {
    __shared__ int hist[SB];
    const int tid = threadIdx.x;
    const int sb = blockIdx.x;
    for (int i = tid; i < SB; i += 256) hist[i] = 0;
    __syncthreads();
    const int cnt = min(gcur_s[sb], SCAP);
    const unsigned short* base = sreg + (size_t)sb * SCAP;
    for (int i = tid; i < cnt; i += 256) atomicAdd(&hist[base[i]], 1);
    __syncthreads();
    for (int t = tid; t < SB; t += 256) {
        int node = sb * SB + t;
        if (node < Nn) norm_s[node] = rsqrtf(fmaxf((float)hist[t], 1.0f));
    }
}

// ---------------- per-half-bucket counting sort -> exact CSR ----------------
// WG j owns nodes [j*256, j*256+256) = half (j&1) of super-bucket (j>>1).

__global__ void csr2_kernel(const int* __restrict__ dreg, const int* __restrict__ gcur_d,
                            int* __restrict__ csr, int* __restrict__ starts,
                            int* __restrict__ ends, float* __restrict__ norm_d, int Nn) {
    __shared__ int hist[256], excl[256], cur[256];
    __shared__ int sorted[CAP2];
    __shared__ int tot_s;
    const int tid = threadIdx.x;
    const int j = blockIdx.x;
    const int sb = j >> 1, half = j & 1;
    const int cnt = min(gcur_d[sb], CAP1);
    const int* reg = dreg + (size_t)sb * CAP1;

    hist[tid] = 0;
    __syncthreads();

    for (int i = tid; i < cnt; i += 256) {
        int pe = reg[i];
        if (((pe >> 25) & 1) == half) atomicAdd(&hist[(pe >> 17) & 255], 1);
    }
    __syncthreads();

    // exclusive scan over 256 (Hillis-Steele)
    excl[tid] = hist[tid];
    __syncthreads();
    for (int off = 1; off < 256; off <<= 1) {
        int v = (tid >= off) ? excl[tid - off] : 0;
        __syncthreads();
        excl[tid] += v;
        __syncthreads();
    }
    int deg = hist[tid];
    int st = excl[tid] - deg;
    if (tid == 255) tot_s = min(excl[255], CAP2);
    int node = j * 256 + tid;
    if (node < Nn) {
        int gs = j * CAP2 + st;
        int dcl = min(deg, max(CAP2 - st, 0));
        starts[node] = gs;
        ends[node]   = gs + dcl;
        norm_d[node] = rsqrtf(fmaxf((float)deg, 1.0f));
    }
    cur[tid] = st;
    __syncthreads();

    for (int i = tid; i < cnt; i += 256) {
        int pe = reg[i];
        if (((pe >> 25) & 1) == half) {
            int pos = atomicAdd(&cur[(pe >> 17) & 255], 1);
            if (pos < CAP2) sorted[pos] = pe & SRCMASK;
        }
    }
    __syncthreads();

    const int tot = tot_s;
    for (int i = tid; i < tot; i += 256) csr[(size_t)j * CAP2 + i] = sorted[i];
}

// ---------------- GEMM: H[row,:] = norm[row] * (X[row,:] @ W) ----------------

template <int K>
__global__ void gemm_norm_kernel(const float* __restrict__ X, const float* __restrict__ norm,
                                 const float* __restrict__ W, float* __restrict__ H, int M) {
    constexpr int KS = K + 4;
    __shared__ float sW[K * 64];
    __shared__ float sX[16 * KS];

    const int tid = threadIdx.x;
    const int row0 = blockIdx.x * 16;

    for (int i = tid; i < K * 16; i += 256)
        ((float4*)sW)[i] = ((const float4*)W)[i];
    for (int i = tid; i < 4 * K; i += 256) {
        int eo = i * 4;
        int r = eo / K, k = eo % K;
        int gr = row0 + r;
        float4 v = (gr < M) ? ((const float4*)(X + (size_t)gr * K))[k >> 2]
                            : make_float4(0.f, 0.f, 0.f, 0.f);
        ((float4*)(sX + r * KS))[k >> 2] = v;
    }
    __syncthreads();

    const int c4 = tid & 15;
    const int r  = tid >> 4;
    const int grow = row0 + r;
    const float* xr = sX + r * KS;

    float4 acc = make_float4(0.f, 0.f, 0.f, 0.f);
#pragma unroll 8
    for (int k = 0; k < K; ++k) {
        float xv = xr[k];
        float4 w = ((const float4*)(sW + k * 64))[c4];
        acc.x = fmaf(xv, w.x, acc.x);
        acc.y = fmaf(xv, w.y, acc.y);
        acc.z = fmaf(xv, w.z, acc.z);
        acc.w = fmaf(xv, w.w, acc.w);
    }
    if (grow < M) {
        float nm = norm[grow];
        acc.x *= nm; acc.y *= nm; acc.z *= nm; acc.w *= nm;
        ((float4*)(H + (size_t)grow * 64))[c4] = acc;
    }
}

// ---------------- pull gather + fused epilogue ----------------

__global__ void gather_kernel(const int* __restrict__ starts, const int* __restrict__ ends,
                              const int* __restrict__ csr, const float* __restrict__ H,
                              const float* __restrict__ nd, const float* __restrict__ b,
                              float* __restrict__ X, int Nn) {
    int node = blockIdx.x * 4 + (threadIdx.x >> 6);
    if (node >= Nn) return;                     // wave-uniform
    int lane = threadIdx.x & 63;
    int q = lane >> 4, c = lane & 15;

    int start = starts[node], end = ends[node];
    float4 acc = make_float4(0.f, 0.f, 0.f, 0.f);
    for (int i = start + q; i < end; i += 4) {
        int s = csr[i];
        float4 v = ((const float4*)(H + (size_t)s * 64))[c];
        acc.x += v.x; acc.y += v.y; acc.z += v.z; acc.w += v.w;
    }
#pragma unroll
    for (int m = 16; m <= 32; m <<= 1) {
        acc.x += __shfl_xor(acc.x, m, 64);
        acc.y += __shfl_xor(acc.y, m, 64);
        acc.z += __shfl_xor(acc.z, m, 64);
        acc.w += __shfl_xor(acc.w, m, 64);
    }
    if (q == 0) {
        float nm = nd[node];
        float4 bb = ((const float4*)b)[c];
        float4 r;
        r.x = fmaxf(fmaf(acc.x, nm, bb.x), 0.f);
        r.y = fmaxf(fmaf(acc.y, nm, bb.y), 0.f);
        r.z = fmaxf(fmaf(acc.z, nm, bb.z), 0.f);
        r.w = fmaxf(fmaf(acc.w, nm, bb.w), 0.f);
        ((float4*)(X + (size_t)node * 64))[c] = r;
    }
}

// ---------------- projection (64x8) + softmax ----------------

__global__ void proj_softmax_kernel(const float* __restrict__ X, const float* __restrict__ Wp,
                                    const float* __restrict__ bp, float* __restrict__ out, int M) {
    __shared__ float sW[64 * NLAB];
    __shared__ float sb[NLAB];
    int tid = threadIdx.x;
    for (int i = tid; i < 64 * NLAB; i += 256) sW[i] = Wp[i];
    if (tid < NLAB) sb[tid] = bp[tid];
    __syncthreads();

    int row = blockIdx.x * 256 + tid;
    if (row >= M) return;

    float logit[NLAB];
#pragma unroll
    for (int l = 0; l < NLAB; ++l) logit[l] = sb[l];
    const float4* x4 = (const float4*)(X + (size_t)row * 64);
#pragma unroll 4
    for (int kk = 0; kk < 16; ++kk) {
        float4 v = x4[kk];
        const float xs[4] = {v.x, v.y, v.z, v.w};
#pragma unroll
        for (int j = 0; j < 4; ++j) {
            int k = kk * 4 + j;
            float xv = xs[j];
#pragma unroll
            for (int l = 0; l < NLAB; ++l)
                logit[l] = fmaf(xv, sW[k * NLAB + l], logit[l]);
        }
    }
    float mx = logit[0];
#pragma unroll
    for (int l = 1; l < NLAB; ++l) mx = fmaxf(mx, logit[l]);
    float s = 0.0f;
#pragma unroll
    for (int l = 0; l < NLAB; ++l) { logit[l] = __expf(logit[l] - mx); s += logit[l]; }
    float inv = 1.0f / s;
#pragma unroll
    for (int l = 0; l < NLAB; ++l) out[(size_t)row * NLAB + l] = logit[l] * inv;
}

// ---------------- launch ----------------

extern "C" void kernel_launch(void* const* d_in, const int* in_sizes, int n_in,
                              void* d_out, int out_size, void* d_ws, size_t ws_size,
                              hipStream_t stream) {
    const float* features = (const float*)d_in[0];
    const int*   edge_src = (const int*)d_in[1];
    const int*   edge_dst = (const int*)d_in[2];
    const float* W1 = (const float*)d_in[4];
    const float* b1 = (const float*)d_in[5];
    const float* W2 = (const float*)d_in[6];
    const float* b2 = (const float*)d_in[7];
    const float* Wp = (const float*)d_in[8];
    const float* bp = (const float*)d_in[9];
    float* out = (float*)d_out;

    const int N = NODES;
    const int E = in_sizes[1];

    // ---- workspace layout (~60 MB; dreg/sreg alias h, dead before gemm1) ----
    char* p = (char*)d_ws;
    int*   csr    = (int*)p;            p += sizeof(int) * (size_t)NHALF * CAP2;  // 7.2 MB
    int*   starts = (int*)p;            p += sizeof(int) * N;
    int*   ends   = (int*)p;            p += sizeof(int) * N;
    float* norm_s = (float*)p;          p += sizeof(float) * N;
    float* norm_d = (float*)p;          p += sizeof(float) * N;
    int*   gcur_d = (int*)p;            p += sizeof(int) * NSB;        // zeroed
    int*   gcur_s = (int*)p;            p += sizeof(int) * NSB;        // zeroed
    p = (char*)(((size_t)p + 255) & ~(size_t)255);
    float* h      = (float*)p;          p += sizeof(float) * (size_t)N * 64;  // 25.6 MB
    float* x      = (float*)p;          p += sizeof(float) * (size_t)N * 64;  // 25.6 MB
    // aliases inside h (consumed by shist/csr2 before gemm1 writes h):
    int*            dreg = (int*)h;                                          // 7.06 MB
    unsigned short* sreg = (unsigned short*)((char*)h + sizeof(int) * (size_t)NSB * CAP1); // 3.5 MB

    hipMemsetAsync(gcur_d, 0, sizeof(int) * 2 * NSB, stream);

    // ---- build: partition -> src histogram -> exact CSR ----
    part_kernel<<<(E + PCHUNK - 1) / PCHUNK, 256, 0, stream>>>(edge_src, edge_dst,
                                                               gcur_d, gcur_s, dreg, sreg, E);
    shist_kernel<<<NSB, 256, 0, stream>>>(sreg, gcur_s, norm_s, N);
    csr2_kernel<<<NHALF, 256, 0, stream>>>(dreg, gcur_d, csr, starts, ends, norm_d, N);

    // ---- layer 1 ----
    gemm_norm_kernel<INF><<<(N + 15) / 16, 256, 0, stream>>>(features, norm_s, W1, h, N);
    gather_kernel<<<(N + 3) / 4, 256, 0, stream>>>(starts, ends, csr, h, norm_d, b1, x, N);

    // ---- layer 2 ----
    gemm_norm_kernel<HID><<<(N + 15) / 16, 256, 0, stream>>>(x, norm_s, W2, h, N);
    gather_kernel<<<(N + 3) / 4, 256, 0, stream>>>(starts, ends, csr, h, norm_d, b2, x, N);

    // ---- projection + softmax ----
    proj_softmax_kernel<<<(N + 255) / 256, 256, 0, stream>>>(x, Wp, bp, out, N);
}

// Round 7
// 358.982 us; speedup vs baseline: 1.1342x; 1.0400x over previous
//
#include <hip/hip_runtime.h>
#include <hip/hip_fp16.h>
#include <math.h>

// GCN: 2x GraphConv(norm='both') + projection + softmax.
// N=100000 nodes, E=1600000 edges, feats 128 -> 64 -> 64 -> 8. All fp32 I/O.
//
// R6 post-mortem: gather is random-line L3-BW-bound (181 MB L2-miss traffic
// on a 25.6 MB fp32 h). R7: h stored as fp16 (|h|<~6, rel err 2^-11 << 2%
// tolerance) -> row = 128B = 2 lines instead of 4; demanded lines halve and
// L2 hit rate doubles. CSR build (radix partition, zero random global
// atomics) unchanged from R6.

#define NODES   100000
#define INF     128
#define HID     64
#define NLAB    8

#define SB      512                         // nodes per super-bucket
#define NSB     ((NODES + SB - 1) / SB)     // 196
#define NHALF   ((NODES + 255) / 256)       // 391 half-buckets (256 nodes)
#define CAP1    9000                        // per-sb edge cap (mean 8192, sigma~90)
#define SCAP    9000                        // per-sb src cap
#define CAP2    4600                        // per-half edge cap (mean 4096, sigma~64)
#define PCHUNK  4096                        // edges per part WG
#define PEPT    (PCHUNK / 256)              // 16
#define SRCMASK 0x1FFFF                     // 17 bits

union H4 { short4 s; __half2 h2[2]; };

// ---------------- partition edges by dst>>9; src vals by src>>9 ----------------

__global__ void part_kernel(const int* __restrict__ src, const int* __restrict__ dst,
                            int* __restrict__ gcur_d, int* __restrict__ gcur_s,
                            int* __restrict__ dreg, unsigned short* __restrict__ sreg, int E) {
    __shared__ int hd[NSB], hs[NSB], bd[NSB], bs[NSB];
    const int tid = threadIdx.x;
    const int e0 = blockIdx.x * PCHUNK;

    for (int i = tid; i < NSB; i += 256) { hd[i] = 0; hs[i] = 0; }
    __syncthreads();

    // phase A: LDS histograms; cache edges in registers
    int es[PEPT], ed[PEPT];
#pragma unroll
    for (int i = 0; i < PEPT; ++i) {
        int e = e0 + tid + i * 256;
        if (e < E) {
            es[i] = src[e]; ed[i] = dst[e];
            atomicAdd(&hd[ed[i] >> 9], 1);
            atomicAdd(&hs[es[i] >> 9], 1);
        } else es[i] = -1;
    }
    __syncthreads();

    // phase B: reserve contiguous runs (hot-line far atomics only: 392 addrs)
    for (int b = tid; b < NSB; b += 256) {
        int c = hd[b]; bd[b] = c ? atomicAdd(&gcur_d[b], c) : 0;
        c = hs[b];     bs[b] = c ? atomicAdd(&gcur_s[b], c) : 0;
    }
    __syncthreads();
    for (int b = tid; b < NSB; b += 256) { hd[b] = 0; hs[b] = 0; }
    __syncthreads();

    // phase C: scatter into runs (dst_local<<17 | src; src_local as ushort)
#pragma unroll
    for (int i = 0; i < PEPT; ++i) {
        if (es[i] >= 0) {
            int s = es[i], d = ed[i];
            int kb = d >> 9;
            int pos = bd[kb] + atomicAdd(&hd[kb], 1);
            if (pos < CAP1) dreg[(size_t)kb * CAP1 + pos] = ((d & (SB - 1)) << 17) | s;
            int ks = s >> 9;
            int ps = bs[ks] + atomicAdd(&hs[ks], 1);
            if (ps < SCAP) sreg[(size_t)ks * SCAP + ps] = (unsigned short)(s & (SB - 1));
        }
    }
}

// ---------------- src-degree histogram per super-bucket -> norm_s ----------------

__global__ void shist_kernel(const unsigned short* __restrict__ sreg,
                             const int* __restrict__ gcur_s,
                             float* __restrict__ norm_s, int Nn) {
    __shared__ int hist[SB];
    const int tid = threadIdx.x;
    const int sb = blockIdx.x;
    for (int i = tid; i < SB; i += 256) hist[i] = 0;
    __syncthreads();
    const int cnt = min(gcur_s[sb], SCAP);
    const unsigned short* base = sreg + (size_t)sb * SCAP;
    for (int i = tid; i < cnt; i += 256) atomicAdd(&hist[base[i]], 1);
    __syncthreads();
    for (int t = tid; t < SB; t += 256) {
        int node = sb * SB + t;
        if (node < Nn) norm_s[node] = rsqrtf(fmaxf((float)hist[t], 1.0f));
    }
}

// ---------------- per-half-bucket counting sort -> exact CSR ----------------
// WG j owns nodes [j*256, j*256+256) = half (j&1) of super-bucket (j>>1).

__global__ void csr2_kernel(const int* __restrict__ dreg, const int* __restrict__ gcur_d,
                            int* __restrict__ csr, int* __restrict__ starts,
                            int* __restrict__ ends, float* __restrict__ norm_d, int Nn) {
    __shared__ int hist[256], excl[256], cur[256];
    __shared__ int sorted[CAP2];
    __shared__ int tot_s;
    const int tid = threadIdx.x;
    const int j = blockIdx.x;
    const int sb = j >> 1, half = j & 1;
    const int cnt = min(gcur_d[sb], CAP1);
    const int* reg = dreg + (size_t)sb * CAP1;

    hist[tid] = 0;
    __syncthreads();

    for (int i = tid; i < cnt; i += 256) {
        int pe = reg[i];
        if (((pe >> 25) & 1) == half) atomicAdd(&hist[(pe >> 17) & 255], 1);
    }
    __syncthreads();

    // exclusive scan over 256 (Hillis-Steele)
    excl[tid] = hist[tid];
    __syncthreads();
    for (int off = 1; off < 256; off <<= 1) {
        int v = (tid >= off) ? excl[tid - off] : 0;
        __syncthreads();
        excl[tid] += v;
        __syncthreads();
    }
    int deg = hist[tid];
    int st = excl[tid] - deg;
    if (tid == 255) tot_s = min(excl[255], CAP2);
    int node = j * 256 + tid;
    if (node < Nn) {
        int gs = j * CAP2 + st;
        int dcl = min(deg, max(CAP2 - st, 0));
        starts[node] = gs;
        ends[node]   = gs + dcl;
        norm_d[node] = rsqrtf(fmaxf((float)deg, 1.0f));
    }
    cur[tid] = st;
    __syncthreads();

    for (int i = tid; i < cnt; i += 256) {
        int pe = reg[i];
        if (((pe >> 25) & 1) == half) {
            int pos = atomicAdd(&cur[(pe >> 17) & 255], 1);
            if (pos < CAP2) sorted[pos] = pe & SRCMASK;
        }
    }
    __syncthreads();

    const int tot = tot_s;
    for (int i = tid; i < tot; i += 256) csr[(size_t)j * CAP2 + i] = sorted[i];
}

// ---------------- GEMM: Hh[row,:] = fp16( norm[row] * (X[row,:] @ W) ) ----------------

template <int K>
__global__ void gemm_norm_kernel(const float* __restrict__ X, const float* __restrict__ norm,
                                 const float* __restrict__ W, __half* __restrict__ Hh, int M) {
    constexpr int KS = K + 4;
    __shared__ float sW[K * 64];
    __shared__ float sX[16 * KS];

    const int tid = threadIdx.x;
    const int row0 = blockIdx.x * 16;

    for (int i = tid; i < K * 16; i += 256)
        ((float4*)sW)[i] = ((const float4*)W)[i];
    for (int i = tid; i < 4 * K; i += 256) {
        int eo = i * 4;
        int r = eo / K, k = eo % K;
        int gr = row0 + r;
        float4 v = (gr < M) ? ((const float4*)(X + (size_t)gr * K))[k >> 2]
                            : make_float4(0.f, 0.f, 0.f, 0.f);
        ((float4*)(sX + r * KS))[k >> 2] = v;
    }
    __syncthreads();

    const int c4 = tid & 15;
    const int r  = tid >> 4;
    const int grow = row0 + r;
    const float* xr = sX + r * KS;

    float4 acc = make_float4(0.f, 0.f, 0.f, 0.f);
#pragma unroll 8
    for (int k = 0; k < K; ++k) {
        float xv = xr[k];
        float4 w = ((const float4*)(sW + k * 64))[c4];
        acc.x = fmaf(xv, w.x, acc.x);
        acc.y = fmaf(xv, w.y, acc.y);
        acc.z = fmaf(xv, w.z, acc.z);
        acc.w = fmaf(xv, w.w, acc.w);
    }
    if (grow < M) {
        float nm = norm[grow];
        H4 v;
        v.h2[0] = __floats2half2_rn(acc.x * nm, acc.y * nm);
        v.h2[1] = __floats2half2_rn(acc.z * nm, acc.w * nm);
        ((short4*)(Hh + (size_t)grow * 64))[c4] = v.s;
    }
}

// ---------------- pull gather (fp16 rows) + fused epilogue ----------------
// One wave per dst node. Quarter q handles edges i = start+q, start+q+4, ...;
// lane-in-quarter c reads 4 fp16 cols (8B). Cross-quarter shfl reduce.
// X[n,:] = relu(norm_d[n] * sum_{s in csr(n)} Hh[s,:] + b)

__global__ void gather_kernel(const int* __restrict__ starts, const int* __restrict__ ends,
                              const int* __restrict__ csr, const __half* __restrict__ Hh,
                              const float* __restrict__ nd, const float* __restrict__ b,
                              float* __restrict__ X, int Nn) {
    int node = blockIdx.x * 4 + (threadIdx.x >> 6);
    if (node >= Nn) return;                     // wave-uniform
    int lane = threadIdx.x & 63;
    int q = lane >> 4, c = lane & 15;

    int start = starts[node], end = ends[node];
    float4 acc = make_float4(0.f, 0.f, 0.f, 0.f);
    for (int i = start + q; i < end; i += 4) {
        int s = csr[i];
        H4 v;
        v.s = ((const short4*)(Hh + (size_t)s * 64))[c];
        float2 lo = __half22float2(v.h2[0]);
        float2 hi = __half22float2(v.h2[1]);
        acc.x += lo.x; acc.y += lo.y; acc.z += hi.x; acc.w += hi.y;
    }
#pragma unroll
    for (int m = 16; m <= 32; m <<= 1) {
        acc.x += __shfl_xor(acc.x, m, 64);
        acc.y += __shfl_xor(acc.y, m, 64);
        acc.z += __shfl_xor(acc.z, m, 64);
        acc.w += __shfl_xor(acc.w, m, 64);
    }
    if (q == 0) {
        float nm = nd[node];
        float4 bb = ((const float4*)b)[c];
        float4 r;
        r.x = fmaxf(fmaf(acc.x, nm, bb.x), 0.f);
        r.y = fmaxf(fmaf(acc.y, nm, bb.y), 0.f);
        r.z = fmaxf(fmaf(acc.z, nm, bb.z), 0.f);
        r.w = fmaxf(fmaf(acc.w, nm, bb.w), 0.f);
        ((float4*)(X + (size_t)node * 64))[c] = r;
    }
}

// ---------------- projection (64x8) + softmax ----------------

__global__ void proj_softmax_kernel(const float* __restrict__ X, const float* __restrict__ Wp,
                                    const float* __restrict__ bp, float* __restrict__ out, int M) {
    __shared__ float sW[64 * NLAB];
    __shared__ float sb[NLAB];
    int tid = threadIdx.x;
    for (int i = tid; i < 64 * NLAB; i += 256) sW[i] = Wp[i];
    if (tid < NLAB) sb[tid] = bp[tid];
    __syncthreads();

    int row = blockIdx.x * 256 + tid;
    if (row >= M) return;

    float logit[NLAB];
#pragma unroll
    for (int l = 0; l < NLAB; ++l) logit[l] = sb[l];
    const float4* x4 = (const float4*)(X + (size_t)row * 64);
#pragma unroll 4
    for (int kk = 0; kk < 16; ++kk) {
        float4 v = x4[kk];
        const float xs[4] = {v.x, v.y, v.z, v.w};
#pragma unroll
        for (int j = 0; j < 4; ++j) {
            int k = kk * 4 + j;
            float xv = xs[j];
#pragma unroll
            for (int l = 0; l < NLAB; ++l)
                logit[l] = fmaf(xv, sW[k * NLAB + l], logit[l]);
        }
    }
    float mx = logit[0];
#pragma unroll
    for (int l = 1; l < NLAB; ++l) mx = fmaxf(mx, logit[l]);
    float s = 0.0f;
#pragma unroll
    for (int l = 0; l < NLAB; ++l) { logit[l] = __expf(logit[l] - mx); s += logit[l]; }
    float inv = 1.0f / s;
#pragma unroll
    for (int l = 0; l < NLAB; ++l) out[(size_t)row * NLAB + l] = logit[l] * inv;
}

// ---------------- launch ----------------

extern "C" void kernel_launch(void* const* d_in, const int* in_sizes, int n_in,
                              void* d_out, int out_size, void* d_ws, size_t ws_size,
                              hipStream_t stream) {
    const float* features = (const float*)d_in[0];
    const int*   edge_src = (const int*)d_in[1];
    const int*   edge_dst = (const int*)d_in[2];
    const float* W1 = (const float*)d_in[4];
    const float* b1 = (const float*)d_in[5];
    const float* W2 = (const float*)d_in[6];
    const float* b2 = (const float*)d_in[7];
    const float* Wp = (const float*)d_in[8];
    const float* bp = (const float*)d_in[9];
    float* out = (float*)d_out;

    const int N = NODES;
    const int E = in_sizes[1];

    // ---- workspace layout (~48 MB; dreg/sreg alias h, dead before gemm1) ----
    char* p = (char*)d_ws;
    int*   csr    = (int*)p;            p += sizeof(int) * (size_t)NHALF * CAP2;  // 7.2 MB
    int*   starts = (int*)p;            p += sizeof(int) * N;
    int*   ends   = (int*)p;            p += sizeof(int) * N;
    float* norm_s = (float*)p;          p += sizeof(float) * N;
    float* norm_d = (float*)p;          p += sizeof(float) * N;
    int*   gcur_d = (int*)p;            p += sizeof(int) * NSB;        // zeroed
    int*   gcur_s = (int*)p;            p += sizeof(int) * NSB;        // zeroed
    p = (char*)(((size_t)p + 255) & ~(size_t)255);
    __half* h     = (__half*)p;         p += sizeof(__half) * (size_t)N * 64; // 12.8 MB
    p = (char*)(((size_t)p + 255) & ~(size_t)255);
    float* x      = (float*)p;          p += sizeof(float) * (size_t)N * 64;  // 25.6 MB
    // aliases inside h (consumed by shist/csr2 before gemm1 writes h):
    int*            dreg = (int*)h;                                          // 7.06 MB
    unsigned short* sreg = (unsigned short*)((char*)h + sizeof(int) * (size_t)NSB * CAP1); // 3.5 MB

    hipMemsetAsync(gcur_d, 0, sizeof(int) * 2 * NSB, stream);

    // ---- build: partition -> src histogram -> exact CSR ----
    part_kernel<<<(E + PCHUNK - 1) / PCHUNK, 256, 0, stream>>>(edge_src, edge_dst,
                                                               gcur_d, gcur_s, dreg, sreg, E);
    shist_kernel<<<NSB, 256, 0, stream>>>(sreg, gcur_s, norm_s, N);
    csr2_kernel<<<NHALF, 256, 0, stream>>>(dreg, gcur_d, csr, starts, ends, norm_d, N);

    // ---- layer 1 ----
    gemm_norm_kernel<INF><<<(N + 15) / 16, 256, 0, stream>>>(features, norm_s, W1, h, N);
    gather_kernel<<<(N + 3) / 4, 256, 0, stream>>>(starts, ends, csr, h, norm_d, b1, x, N);

    // ---- layer 2 ----
    gemm_norm_kernel<HID><<<(N + 15) / 16, 256, 0, stream>>>(x, norm_s, W2, h, N);
    gather_kernel<<<(N + 3) / 4, 256, 0, stream>>>(starts, ends, csr, h, norm_d, b2, x, N);

    // ---- projection + softmax ----
    proj_softmax_kernel<<<(N + 255) / 256, 256, 0, stream>>>(x, Wp, bp, out, N);
}

// Round 9
// 318.813 us; speedup vs baseline: 1.2771x; 1.1260x over previous
//
#include <hip/hip_runtime.h>
#include <hip/hip_fp16.h>
#include <math.h>

// GCN: 2x GraphConv(norm='both') + projection + softmax.
// N=100000 nodes, E=1600000 edges, feats 128 -> 64 -> 64 -> 8. All fp32 I/O.
//
// R8 post-mortem: gather read __shfl from lanes whose group had exited the
// per-group-trip-count loop -> undefined (inactive source lane) -> absmax
// 0.067. R9: wave-uniform k-loop (nk = ceil(ecount/8)); shfls always execute
// at full exec; only the loads are predicated (zero-fill when j >= ecount).
// Keeps 8-lanes-per-row int4 loads + 2x independent loads per iteration.

#define NODES   100000
#define INF     128
#define HID     64
#define NLAB    8

#define SB      512                         // nodes per super-bucket
#define NSB     ((NODES + SB - 1) / SB)     // 196
#define NHALF   ((NODES + 255) / 256)       // 391 half-buckets (256 nodes)
#define CAP1    9000                        // per-sb edge cap (mean 8192, sigma~90)
#define SCAP    9000                        // per-sb src cap
#define CAP2    4600                        // per-half edge cap (mean 4096, sigma~64)
#define PCHUNK  4096                        // edges per part WG
#define PEPT    (PCHUNK / 256)              // 16
#define SRCMASK 0x1FFFF                     // 17 bits

union H4 { short4 s; __half2 h2[2]; };
union H8 { int4 i4; __half2 h2[4]; };

// ---------------- partition edges by dst>>9; src vals by src>>9 ----------------

__global__ void part_kernel(const int* __restrict__ src, const int* __restrict__ dst,
                            int* __restrict__ gcur_d, int* __restrict__ gcur_s,
                            int* __restrict__ dreg, unsigned short* __restrict__ sreg, int E) {
    __shared__ int hd[NSB], hs[NSB], bd[NSB], bs[NSB];
    const int tid = threadIdx.x;
    const int e0 = blockIdx.x * PCHUNK;

    for (int i = tid; i < NSB; i += 256) { hd[i] = 0; hs[i] = 0; }
    __syncthreads();

    // phase A: LDS histograms; cache edges in registers
    int es[PEPT], ed[PEPT];
#pragma unroll
    for (int i = 0; i < PEPT; ++i) {
        int e = e0 + tid + i * 256;
        if (e < E) {
            es[i] = src[e]; ed[i] = dst[e];
            atomicAdd(&hd[ed[i] >> 9], 1);
            atomicAdd(&hs[es[i] >> 9], 1);
        } else es[i] = -1;
    }
    __syncthreads();

    // phase B: reserve contiguous runs (hot-line far atomics only: 392 addrs)
    for (int b = tid; b < NSB; b += 256) {
        int c = hd[b]; bd[b] = c ? atomicAdd(&gcur_d[b], c) : 0;
        c = hs[b];     bs[b] = c ? atomicAdd(&gcur_s[b], c) : 0;
    }
    __syncthreads();
    for (int b = tid; b < NSB; b += 256) { hd[b] = 0; hs[b] = 0; }
    __syncthreads();

    // phase C: scatter into runs (dst_local<<17 | src; src_local as ushort)
#pragma unroll
    for (int i = 0; i < PEPT; ++i) {
        if (es[i] >= 0) {
            int s = es[i], d = ed[i];
            int kb = d >> 9;
            int pos = bd[kb] + atomicAdd(&hd[kb], 1);
            if (pos < CAP1) dreg[(size_t)kb * CAP1 + pos] = ((d & (SB - 1)) << 17) | s;
            int ks = s >> 9;
            int ps = bs[ks] + atomicAdd(&hs[ks], 1);
            if (ps < SCAP) sreg[(size_t)ks * SCAP + ps] = (unsigned short)(s & (SB - 1));
        }
    }
}

// ---------------- src-degree histogram per super-bucket -> norm_s ----------------

__global__ void shist_kernel(const unsigned short* __restrict__ sreg,
                             const int* __restrict__ gcur_s,
                             float* __restrict__ norm_s, int Nn) {
    __shared__ int hist[SB];
    const int tid = threadIdx.x;
    const int sb = blockIdx.x;
    for (int i = tid; i < SB; i += 256) hist[i] = 0;
    __syncthreads();
    const int cnt = min(gcur_s[sb], SCAP);
    const unsigned short* base = sreg + (size_t)sb * SCAP;
    for (int i = tid; i < cnt; i += 256) atomicAdd(&hist[base[i]], 1);
    __syncthreads();
    for (int t = tid; t < SB; t += 256) {
        int node = sb * SB + t;
        if (node < Nn) norm_s[node] = rsqrtf(fmaxf((float)hist[t], 1.0f));
    }
}

// ---------------- per-half-bucket counting sort -> exact CSR ----------------
// WG j owns nodes [j*256, j*256+256) = half (j&1) of super-bucket (j>>1).

__global__ void csr2_kernel(const int* __restrict__ dreg, const int* __restrict__ gcur_d,
                            int* __restrict__ csr, int* __restrict__ starts,
                            int* __restrict__ ends, float* __restrict__ norm_d, int Nn) {
    __shared__ int hist[256], excl[256], cur[256];
    __shared__ int sorted[CAP2];
    __shared__ int tot_s;
    const int tid = threadIdx.x;
    const int j = blockIdx.x;
    const int sb = j >> 1, half = j & 1;
    const int cnt = min(gcur_d[sb], CAP1);
    const int* reg = dreg + (size_t)sb * CAP1;

    hist[tid] = 0;
    __syncthreads();

    for (int i = tid; i < cnt; i += 256) {
        int pe = reg[i];
        if (((pe >> 25) & 1) == half) atomicAdd(&hist[(pe >> 17) & 255], 1);
    }
    __syncthreads();

    // exclusive scan over 256 (Hillis-Steele)
    excl[tid] = hist[tid];
    __syncthreads();
    for (int off = 1; off < 256; off <<= 1) {
        int v = (tid >= off) ? excl[tid - off] : 0;
        __syncthreads();
        excl[tid] += v;
        __syncthreads();
    }
    int deg = hist[tid];
    int st = excl[tid] - deg;
    if (tid == 255) tot_s = min(excl[255], CAP2);
    int node = j * 256 + tid;
    if (node < Nn) {
        int gs = j * CAP2 + st;
        int dcl = min(deg, max(CAP2 - st, 0));
        starts[node] = gs;
        ends[node]   = gs + dcl;
        norm_d[node] = rsqrtf(fmaxf((float)deg, 1.0f));
    }
    cur[tid] = st;
    __syncthreads();

    for (int i = tid; i < cnt; i += 256) {
        int pe = reg[i];
        if (((pe >> 25) & 1) == half) {
            int pos = atomicAdd(&cur[(pe >> 17) & 255], 1);
            if (pos < CAP2) sorted[pos] = pe & SRCMASK;
        }
    }
    __syncthreads();

    const int tot = tot_s;
    for (int i = tid; i < tot; i += 256) csr[(size_t)j * CAP2 + i] = sorted[i];
}

// ---------------- GEMM: Hh[row,:] = fp16( norm[row] * (X[row,:] @ W) ) ----------------

template <int K>
__global__ void gemm_norm_kernel(const float* __restrict__ X, const float* __restrict__ norm,
                                 const float* __restrict__ W, __half* __restrict__ Hh, int M) {
    constexpr int KS = K + 4;
    __shared__ float sW[K * 64];
    __shared__ float sX[16 * KS];

    const int tid = threadIdx.x;
    const int row0 = blockIdx.x * 16;

    for (int i = tid; i < K * 16; i += 256)
        ((float4*)sW)[i] = ((const float4*)W)[i];
    for (int i = tid; i < 4 * K; i += 256) {
        int eo = i * 4;
        int r = eo / K, k = eo % K;
        int gr = row0 + r;
        float4 v = (gr < M) ? ((const float4*)(X + (size_t)gr * K))[k >> 2]
                            : make_float4(0.f, 0.f, 0.f, 0.f);
        ((float4*)(sX + r * KS))[k >> 2] = v;
    }
    __syncthreads();

    const int c4 = tid & 15;
    const int r  = tid >> 4;
    const int grow = row0 + r;
    const float* xr = sX + r * KS;

    float4 acc = make_float4(0.f, 0.f, 0.f, 0.f);
#pragma unroll 8
    for (int k = 0; k < K; ++k) {
        float xv = xr[k];
        float4 w = ((const float4*)(sW + k * 64))[c4];
        acc.x = fmaf(xv, w.x, acc.x);
        acc.y = fmaf(xv, w.y, acc.y);
        acc.z = fmaf(xv, w.z, acc.z);
        acc.w = fmaf(xv, w.w, acc.w);
    }
    if (grow < M) {
        float nm = norm[grow];
        H4 v;
        v.h2[0] = __floats2half2_rn(acc.x * nm, acc.y * nm);
        v.h2[1] = __floats2half2_rn(acc.z * nm, acc.w * nm);
        ((short4*)(Hh + (size_t)grow * 64))[c4] = v.s;
    }
}

// ---------------- pull gather (fp16 rows), MLP-widened, uniform-exec shfl ----------------
// One wave per node. Coalesced csr prefetch: lane l holds csr[base+l].
// Group g=lane>>3 handles edge slots j = g+8k; k-loop bound nk=ceil(ecount/8)
// is WAVE-UNIFORM so every __shfl runs at full exec. Loads predicated
// (zero-fill regs when j >= ecount). 2 independent int4 loads per iteration.

__global__ void gather_kernel(const int* __restrict__ starts, const int* __restrict__ ends,
                              const int* __restrict__ csr, const __half* __restrict__ Hh,
                              const float* __restrict__ nd, const float* __restrict__ b,
                              float* __restrict__ X, int Nn) {
    int node = blockIdx.x * 4 + (threadIdx.x >> 6);
    if (node >= Nn) return;                     // wave-uniform
    const int lane = threadIdx.x & 63;
    const int g = lane >> 3;                    // edge slot group 0..7
    const int c = lane & 7;                     // 16B col chunk

    const int start = starts[node], end = ends[node];
    float acc[8] = {0.f, 0.f, 0.f, 0.f, 0.f, 0.f, 0.f, 0.f};

    for (int base = start; base < end; base += 64) {
        int idx = base + lane;
        int pe = (idx < end) ? csr[idx] : 0;    // one coalesced load / 64 edges
        int ecount = min(end - base, 64);
        int nk = (ecount + 7) >> 3;             // wave-uniform trip count

        for (int k = 0; k < nk; k += 2) {
            int j0 = g + 8 * k;                 // <= 55
            int j1 = j0 + 8;                    // <= 63
            int s0 = __shfl(pe, j0, 64);        // full-wave exec (uniform bounds)
            int s1 = __shfl(pe, j1, 64);
            H8 v0, v1;
            if (j0 < ecount) v0.i4 = ((const int4*)(Hh + (size_t)s0 * 64))[c];
            else             v0.i4 = make_int4(0, 0, 0, 0);
            if (j1 < ecount) v1.i4 = ((const int4*)(Hh + (size_t)s1 * 64))[c];
            else             v1.i4 = make_int4(0, 0, 0, 0);
#pragma unroll
            for (int t = 0; t < 4; ++t) {
                float2 f0 = __half22float2(v0.h2[t]);
                float2 f1 = __half22float2(v1.h2[t]);
                acc[2 * t]     += f0.x + f1.x;
                acc[2 * t + 1] += f0.y + f1.y;
            }
        }
    }

    // reduce over g (lane bits 3,4,5)
#pragma unroll
    for (int m = 8; m <= 32; m <<= 1) {
#pragma unroll
        for (int k = 0; k < 8; ++k)
            acc[k] += __shfl_xor(acc[k], m, 64);
    }

    if (g == 0) {                               // lanes 0..7 write 8 cols each
        float nm = nd[node];
        float4 b0 = ((const float4*)b)[2 * c];
        float4 b1 = ((const float4*)b)[2 * c + 1];
        float4 r0, r1;
        r0.x = fmaxf(fmaf(acc[0], nm, b0.x), 0.f);
        r0.y = fmaxf(fmaf(acc[1], nm, b0.y), 0.f);
        r0.z = fmaxf(fmaf(acc[2], nm, b0.z), 0.f);
        r0.w = fmaxf(fmaf(acc[3], nm, b0.w), 0.f);
        r1.x = fmaxf(fmaf(acc[4], nm, b1.x), 0.f);
        r1.y = fmaxf(fmaf(acc[5], nm, b1.y), 0.f);
        r1.z = fmaxf(fmaf(acc[6], nm, b1.z), 0.f);
        r1.w = fmaxf(fmaf(acc[7], nm, b1.w), 0.f);
        ((float4*)(X + (size_t)node * 64))[2 * c]     = r0;
        ((float4*)(X + (size_t)node * 64))[2 * c + 1] = r1;
    }
}

// ---------------- projection (64x8) + softmax ----------------

__global__ void proj_softmax_kernel(const float* __restrict__ X, const float* __restrict__ Wp,
                                    const float* __restrict__ bp, float* __restrict__ out, int M) {
    __shared__ float sW[64 * NLAB];
    __shared__ float sb[NLAB];
    int tid = threadIdx.x;
    for (int i = tid; i < 64 * NLAB; i += 256) sW[i] = Wp[i];
    if (tid < NLAB) sb[tid] = bp[tid];
    __syncthreads();

    int row = blockIdx.x * 256 + tid;
    if (row >= M) return;

    float logit[NLAB];
#pragma unroll
    for (int l = 0; l < NLAB; ++l) logit[l] = sb[l];
    const float4* x4 = (const float4*)(X + (size_t)row * 64);
#pragma unroll 4
    for (int kk = 0; kk < 16; ++kk) {
        float4 v = x4[kk];
        const float xs[4] = {v.x, v.y, v.z, v.w};
#pragma unroll
        for (int j = 0; j < 4; ++j) {
            int k = kk * 4 + j;
            float xv = xs[j];
#pragma unroll
            for (int l = 0; l < NLAB; ++l)
                logit[l] = fmaf(xv, sW[k * NLAB + l], logit[l]);
        }
    }
    float mx = logit[0];
#pragma unroll
    for (int l = 1; l < NLAB; ++l) mx = fmaxf(mx, logit[l]);
    float s = 0.0f;
#pragma unroll
    for (int l = 0; l < NLAB; ++l) { logit[l] = __expf(logit[l] - mx); s += logit[l]; }
    float inv = 1.0f / s;
#pragma unroll
    for (int l = 0; l < NLAB; ++l) out[(size_t)row * NLAB + l] = logit[l] * inv;
}

// ---------------- launch ----------------

extern "C" void kernel_launch(void* const* d_in, const int* in_sizes, int n_in,
                              void* d_out, int out_size, void* d_ws, size_t ws_size,
                              hipStream_t stream) {
    const float* features = (const float*)d_in[0];
    const int*   edge_src = (const int*)d_in[1];
    const int*   edge_dst = (const int*)d_in[2];
    const float* W1 = (const float*)d_in[4];
    const float* b1 = (const float*)d_in[5];
    const float* W2 = (const float*)d_in[6];
    const float* b2 = (const float*)d_in[7];
    const float* Wp = (const float*)d_in[8];
    const float* bp = (const float*)d_in[9];
    float* out = (float*)d_out;

    const int N = NODES;
    const int E = in_sizes[1];

    // ---- workspace layout (~48 MB; dreg/sreg alias h, dead before gemm1) ----
    char* p = (char*)d_ws;
    int*   csr    = (int*)p;            p += sizeof(int) * (size_t)NHALF * CAP2;  // 7.2 MB
    int*   starts = (int*)p;            p += sizeof(int) * N;
    int*   ends   = (int*)p;            p += sizeof(int) * N;
    float* norm_s = (float*)p;          p += sizeof(float) * N;
    float* norm_d = (float*)p;          p += sizeof(float) * N;
    int*   gcur_d = (int*)p;            p += sizeof(int) * NSB;        // zeroed
    int*   gcur_s = (int*)p;            p += sizeof(int) * NSB;        // zeroed
    p = (char*)(((size_t)p + 255) & ~(size_t)255);
    __half* h     = (__half*)p;         p += sizeof(__half) * (size_t)N * 64; // 12.8 MB
    p = (char*)(((size_t)p + 255) & ~(size_t)255);
    float* x      = (float*)p;          p += sizeof(float) * (size_t)N * 64;  // 25.6 MB
    // aliases inside h (consumed by shist/csr2 before gemm1 writes h):
    int*            dreg = (int*)h;                                          // 7.06 MB
    unsigned short* sreg = (unsigned short*)((char*)h + sizeof(int) * (size_t)NSB * CAP1); // 3.5 MB

    hipMemsetAsync(gcur_d, 0, sizeof(int) * 2 * NSB, stream);

    // ---- build: partition -> src histogram -> exact CSR ----
    part_kernel<<<(E + PCHUNK - 1) / PCHUNK, 256, 0, stream>>>(edge_src, edge_dst,
                                                               gcur_d, gcur_s, dreg, sreg, E);
    shist_kernel<<<NSB, 256, 0, stream>>>(sreg, gcur_s, norm_s, N);
    csr2_kernel<<<NHALF, 256, 0, stream>>>(dreg, gcur_d, csr, starts, ends, norm_d, N);

    // ---- layer 1 ----
    gemm_norm_kernel<INF><<<(N + 15) / 16, 256, 0, stream>>>(features, norm_s, W1, h, N);
    gather_kernel<<<(N + 3) / 4, 256, 0, stream>>>(starts, ends, csr, h, norm_d, b1, x, N);

    // ---- layer 2 ----
    gemm_norm_kernel<HID><<<(N + 15) / 16, 256, 0, stream>>>(x, norm_s, W2, h, N);
    gather_kernel<<<(N + 3) / 4, 256, 0, stream>>>(starts, ends, csr, h, norm_d, b2, x, N);

    // ---- projection + softmax ----
    proj_softmax_kernel<<<(N + 255) / 256, 256, 0, stream>>>(x, Wp, bp, out, N);
}

// Round 10
// 310.241 us; speedup vs baseline: 1.3124x; 1.0276x over previous
//
#include <hip/hip_runtime.h>
#include <hip/hip_fp16.h>
#include <math.h>

// GCN: 2x GraphConv(norm='both') + projection + softmax.
// N=100000 nodes, E=1600000 edges, feats 128 -> 64 -> 64 -> 8. All fp32 I/O.
//
// R9 post-mortem: gemm was LDS-byte bound (2.5 B/FLOP; 16 MB/CU at 128 B/cyc
// = 52 us, matching 56 observed). R10: 64x64 block, 4 rows x 4 cols per
// thread -> 1 B/FLOP (w-float4 amortized over 4 rows, x via 16-lane
// broadcast scalar reads). Gather / CSR build unchanged from R9.

#define NODES   100000
#define INF     128
#define HID     64
#define NLAB    8

#define SB      512                         // nodes per super-bucket
#define NSB     ((NODES + SB - 1) / SB)     // 196
#define NHALF   ((NODES + 255) / 256)       // 391 half-buckets (256 nodes)
#define CAP1    9000                        // per-sb edge cap (mean 8192, sigma~90)
#define SCAP    9000                        // per-sb src cap
#define CAP2    4600                        // per-half edge cap (mean 4096, sigma~64)
#define PCHUNK  4096                        // edges per part WG
#define PEPT    (PCHUNK / 256)              // 16
#define SRCMASK 0x1FFFF                     // 17 bits

union H4 { int2 i2; __half2 h2[2]; };
union H8 { int4 i4; __half2 h2[4]; };

// ---------------- partition edges by dst>>9; src vals by src>>9 ----------------

__global__ void part_kernel(const int* __restrict__ src, const int* __restrict__ dst,
                            int* __restrict__ gcur_d, int* __restrict__ gcur_s,
                            int* __restrict__ dreg, unsigned short* __restrict__ sreg, int E) {
    __shared__ int hd[NSB], hs[NSB], bd[NSB], bs[NSB];
    const int tid = threadIdx.x;
    const int e0 = blockIdx.x * PCHUNK;

    for (int i = tid; i < NSB; i += 256) { hd[i] = 0; hs[i] = 0; }
    __syncthreads();

    // phase A: LDS histograms; cache edges in registers
    int es[PEPT], ed[PEPT];
#pragma unroll
    for (int i = 0; i < PEPT; ++i) {
        int e = e0 + tid + i * 256;
        if (e < E) {
            es[i] = src[e]; ed[i] = dst[e];
            atomicAdd(&hd[ed[i] >> 9], 1);
            atomicAdd(&hs[es[i] >> 9], 1);
        } else es[i] = -1;
    }
    __syncthreads();

    // phase B: reserve contiguous runs (hot-line far atomics only: 392 addrs)
    for (int b = tid; b < NSB; b += 256) {
        int c = hd[b]; bd[b] = c ? atomicAdd(&gcur_d[b], c) : 0;
        c = hs[b];     bs[b] = c ? atomicAdd(&gcur_s[b], c) : 0;
    }
    __syncthreads();
    for (int b = tid; b < NSB; b += 256) { hd[b] = 0; hs[b] = 0; }
    __syncthreads();

    // phase C: scatter into runs (dst_local<<17 | src; src_local as ushort)
#pragma unroll
    for (int i = 0; i < PEPT; ++i) {
        if (es[i] >= 0) {
            int s = es[i], d = ed[i];
            int kb = d >> 9;
            int pos = bd[kb] + atomicAdd(&hd[kb], 1);
            if (pos < CAP1) dreg[(size_t)kb * CAP1 + pos] = ((d & (SB - 1)) << 17) | s;
            int ks = s >> 9;
            int ps = bs[ks] + atomicAdd(&hs[ks], 1);
            if (ps < SCAP) sreg[(size_t)ks * SCAP + ps] = (unsigned short)(s & (SB - 1));
        }
    }
}

// ---------------- src-degree histogram per super-bucket -> norm_s ----------------

__global__ void shist_kernel(const unsigned short* __restrict__ sreg,
                             const int* __restrict__ gcur_s,
                             float* __restrict__ norm_s, int Nn) {
    __shared__ int hist[SB];
    const int tid = threadIdx.x;
    const int sb = blockIdx.x;
    for (int i = tid; i < SB; i += 256) hist[i] = 0;
    __syncthreads();
    const int cnt = min(gcur_s[sb], SCAP);
    const unsigned short* base = sreg + (size_t)sb * SCAP;
    for (int i = tid; i < cnt; i += 256) atomicAdd(&hist[base[i]], 1);
    __syncthreads();
    for (int t = tid; t < SB; t += 256) {
        int node = sb * SB + t;
        if (node < Nn) norm_s[node] = rsqrtf(fmaxf((float)hist[t], 1.0f));
    }
}

// ---------------- per-half-bucket counting sort -> exact CSR ----------------
// WG j owns nodes [j*256, j*256+256) = half (j&1) of super-bucket (j>>1).

__global__ void csr2_kernel(const int* __restrict__ dreg, const int* __restrict__ gcur_d,
                            int* __restrict__ csr, int* __restrict__ starts,
                            int* __restrict__ ends, float* __restrict__ norm_d, int Nn) {
    __shared__ int hist[256], excl[256], cur[256];
    __shared__ int sorted[CAP2];
    __shared__ int tot_s;
    const int tid = threadIdx.x;
    const int j = blockIdx.x;
    const int sb = j >> 1, half = j & 1;
    const int cnt = min(gcur_d[sb], CAP1);
    const int* reg = dreg + (size_t)sb * CAP1;

    hist[tid] = 0;
    __syncthreads();

    for (int i = tid; i < cnt; i += 256) {
        int pe = reg[i];
        if (((pe >> 25) & 1) == half) atomicAdd(&hist[(pe >> 17) & 255], 1);
    }
    __syncthreads();

    // exclusive scan over 256 (Hillis-Steele)
    excl[tid] = hist[tid];
    __syncthreads();
    for (int off = 1; off < 256; off <<= 1) {
        int v = (tid >= off) ? excl[tid - off] : 0;
        __syncthreads();
        excl[tid] += v;
        __syncthreads();
    }
    int deg = hist[tid];
    int st = excl[tid] - deg;
    if (tid == 255) tot_s = min(excl[255], CAP2);
    int node = j * 256 + tid;
    if (node < Nn) {
        int gs = j * CAP2 + st;
        int dcl = min(deg, max(CAP2 - st, 0));
        starts[node] = gs;
        ends[node]   = gs + dcl;
        norm_d[node] = rsqrtf(fmaxf((float)deg, 1.0f));
    }
    cur[tid] = st;
    __syncthreads();

    for (int i = tid; i < cnt; i += 256) {
        int pe = reg[i];
        if (((pe >> 25) & 1) == half) {
            int pos = atomicAdd(&cur[(pe >> 17) & 255], 1);
            if (pos < CAP2) sorted[pos] = pe & SRCMASK;
        }
    }
    __syncthreads();

    const int tot = tot_s;
    for (int i = tid; i < tot; i += 256) csr[(size_t)j * CAP2 + i] = sorted[i];
}

// ---------------- GEMM: Hh[row,:] = fp16( norm[row] * (X[row,:] @ W) ) ----------------
// 64 rows x 64 cols per block; thread (rg,cg) computes rows rg*4..+3, cols
// cg*4..+3. Per k: 4 scalar x reads (16-lane broadcast) + 1 w float4 = 32 B
// LDS for 32 FLOP (1 B/FLOP, vs 2.5 in R9's 16-row layout).

template <int K>
__global__ void gemm_norm_kernel(const float* __restrict__ X, const float* __restrict__ norm,
                                 const float* __restrict__ W, __half* __restrict__ Hh, int M) {
    constexpr int KS = K + 4;                   // pad keeps 4-row x-reads 2-way max
    constexpr int KC = K / 4;
    __shared__ float sW[K * 64];
    __shared__ float sX[64 * KS];

    const int tid = threadIdx.x;
    const int row0 = blockIdx.x * 64;

    for (int i = tid; i < K * 16; i += 256)
        ((float4*)sW)[i] = ((const float4*)W)[i];
    for (int i = tid; i < 64 * KC; i += 256) {
        int r = i / KC, kc = i % KC;            // consecutive lanes: same row, adj kc (coalesced)
        int gr = row0 + r;
        float4 v = (gr < M) ? ((const float4*)(X + (size_t)gr * K))[kc]
                            : make_float4(0.f, 0.f, 0.f, 0.f);
        ((float4*)(sX + r * KS))[kc] = v;
    }
    __syncthreads();

    const int cg = tid & 15;                    // col group (4 cols)
    const int rg = tid >> 4;                    // row group (4 rows)
    const float* x0 = sX + (rg * 4 + 0) * KS;
    const float* x1 = sX + (rg * 4 + 1) * KS;
    const float* x2 = sX + (rg * 4 + 2) * KS;
    const float* x3 = sX + (rg * 4 + 3) * KS;
    const float4* w4 = (const float4*)sW + cg;

    float4 a0 = make_float4(0.f, 0.f, 0.f, 0.f);
    float4 a1 = a0, a2 = a0, a3 = a0;

#pragma unroll 4
    for (int k = 0; k < K; ++k) {
        float4 w = w4[k * 16];
        float v0 = x0[k], v1 = x1[k], v2 = x2[k], v3 = x3[k];
        a0.x = fmaf(v0, w.x, a0.x); a0.y = fmaf(v0, w.y, a0.y);
        a0.z = fmaf(v0, w.z, a0.z); a0.w = fmaf(v0, w.w, a0.w);
        a1.x = fmaf(v1, w.x, a1.x); a1.y = fmaf(v1, w.y, a1.y);
        a1.z = fmaf(v1, w.z, a1.z); a1.w = fmaf(v1, w.w, a1.w);
        a2.x = fmaf(v2, w.x, a2.x); a2.y = fmaf(v2, w.y, a2.y);
        a2.z = fmaf(v2, w.z, a2.z); a2.w = fmaf(v2, w.w, a2.w);
        a3.x = fmaf(v3, w.x, a3.x); a3.y = fmaf(v3, w.y, a3.y);
        a3.z = fmaf(v3, w.z, a3.z); a3.w = fmaf(v3, w.w, a3.w);
    }

    float4 accs[4] = {a0, a1, a2, a3};
#pragma unroll
    for (int i = 0; i < 4; ++i) {
        int grow = row0 + rg * 4 + i;
        if (grow < M) {
            float nm = norm[grow];
            H4 v;
            v.h2[0] = __floats2half2_rn(accs[i].x * nm, accs[i].y * nm);
            v.h2[1] = __floats2half2_rn(accs[i].z * nm, accs[i].w * nm);
            ((int2*)(Hh + (size_t)grow * 64))[cg] = v.i2;
        }
    }
}

// ---------------- pull gather (fp16 rows), MLP-widened, uniform-exec shfl ----------------

__global__ void gather_kernel(const int* __restrict__ starts, const int* __restrict__ ends,
                              const int* __restrict__ csr, const __half* __restrict__ Hh,
                              const float* __restrict__ nd, const float* __restrict__ b,
                              float* __restrict__ X, int Nn) {
    int node = blockIdx.x * 4 + (threadIdx.x >> 6);
    if (node >= Nn) return;                     // wave-uniform
    const int lane = threadIdx.x & 63;
    const int g = lane >> 3;                    // edge slot group 0..7
    const int c = lane & 7;                     // 16B col chunk

    const int start = starts[node], end = ends[node];
    float acc[8] = {0.f, 0.f, 0.f, 0.f, 0.f, 0.f, 0.f, 0.f};

    for (int base = start; base < end; base += 64) {
        int idx = base + lane;
        int pe = (idx < end) ? csr[idx] : 0;    // one coalesced load / 64 edges
        int ecount = min(end - base, 64);
        int nk = (ecount + 7) >> 3;             // wave-uniform trip count

        for (int k = 0; k < nk; k += 2) {
            int j0 = g + 8 * k;                 // <= 55
            int j1 = j0 + 8;                    // <= 63
            int s0 = __shfl(pe, j0, 64);        // full-wave exec (uniform bounds)
            int s1 = __shfl(pe, j1, 64);
            H8 v0, v1;
            if (j0 < ecount) v0.i4 = ((const int4*)(Hh + (size_t)s0 * 64))[c];
            else             v0.i4 = make_int4(0, 0, 0, 0);
            if (j1 < ecount) v1.i4 = ((const int4*)(Hh + (size_t)s1 * 64))[c];
            else             v1.i4 = make_int4(0, 0, 0, 0);
#pragma unroll
            for (int t = 0; t < 4; ++t) {
                float2 f0 = __half22float2(v0.h2[t]);
                float2 f1 = __half22float2(v1.h2[t]);
                acc[2 * t]     += f0.x + f1.x;
                acc[2 * t + 1] += f0.y + f1.y;
            }
        }
    }

    // reduce over g (lane bits 3,4,5)
#pragma unroll
    for (int m = 8; m <= 32; m <<= 1) {
#pragma unroll
        for (int k = 0; k < 8; ++k)
            acc[k] += __shfl_xor(acc[k], m, 64);
    }

    if (g == 0) {                               // lanes 0..7 write 8 cols each
        float nm = nd[node];
        float4 b0 = ((const float4*)b)[2 * c];
        float4 b1 = ((const float4*)b)[2 * c + 1];
        float4 r0, r1;
        r0.x = fmaxf(fmaf(acc[0], nm, b0.x), 0.f);
        r0.y = fmaxf(fmaf(acc[1], nm, b0.y), 0.f);
        r0.z = fmaxf(fmaf(acc[2], nm, b0.z), 0.f);
        r0.w = fmaxf(fmaf(acc[3], nm, b0.w), 0.f);
        r1.x = fmaxf(fmaf(acc[4], nm, b1.x), 0.f);
        r1.y = fmaxf(fmaf(acc[5], nm, b1.y), 0.f);
        r1.z = fmaxf(fmaf(acc[6], nm, b1.z), 0.f);
        r1.w = fmaxf(fmaf(acc[7], nm, b1.w), 0.f);
        ((float4*)(X + (size_t)node * 64))[2 * c]     = r0;
        ((float4*)(X + (size_t)node * 64))[2 * c + 1] = r1;
    }
}

// ---------------- projection (64x8) + softmax ----------------

__global__ void proj_softmax_kernel(const float* __restrict__ X, const float* __restrict__ Wp,
                                    const float* __restrict__ bp, float* __restrict__ out, int M) {
    __shared__ float sW[64 * NLAB];
    __shared__ float sb[NLAB];
    int tid = threadIdx.x;
    for (int i = tid; i < 64 * NLAB; i += 256) sW[i] = Wp[i];
    if (tid < NLAB) sb[tid] = bp[tid];
    __syncthreads();

    int row = blockIdx.x * 256 + tid;
    if (row >= M) return;

    float logit[NLAB];
#pragma unroll
    for (int l = 0; l < NLAB; ++l) logit[l] = sb[l];
    const float4* x4 = (const float4*)(X + (size_t)row * 64);
#pragma unroll 4
    for (int kk = 0; kk < 16; ++kk) {
        float4 v = x4[kk];
        const float xs[4] = {v.x, v.y, v.z, v.w};
#pragma unroll
        for (int j = 0; j < 4; ++j) {
            int k = kk * 4 + j;
            float xv = xs[j];
#pragma unroll
            for (int l = 0; l < NLAB; ++l)
                logit[l] = fmaf(xv, sW[k * NLAB + l], logit[l]);
        }
    }
    float mx = logit[0];
#pragma unroll
    for (int l = 1; l < NLAB; ++l) mx = fmaxf(mx, logit[l]);
    float s = 0.0f;
#pragma unroll
    for (int l = 0; l < NLAB; ++l) { logit[l] = __expf(logit[l] - mx); s += logit[l]; }
    float inv = 1.0f / s;
#pragma unroll
    for (int l = 0; l < NLAB; ++l) out[(size_t)row * NLAB + l] = logit[l] * inv;
}

// ---------------- launch ----------------

extern "C" void kernel_launch(void* const* d_in, const int* in_sizes, int n_in,
                              void* d_out, int out_size, void* d_ws, size_t ws_size,
                              hipStream_t stream) {
    const float* features = (const float*)d_in[0];
    const int*   edge_src = (const int*)d_in[1];
    const int*   edge_dst = (const int*)d_in[2];
    const float* W1 = (const float*)d_in[4];
    const float* b1 = (const float*)d_in[5];
    const float* W2 = (const float*)d_in[6];
    const float* b2 = (const float*)d_in[7];
    const float* Wp = (const float*)d_in[8];
    const float* bp = (const float*)d_in[9];
    float* out = (float*)d_out;

    const int N = NODES;
    const int E = in_sizes[1];

    // ---- workspace layout (~48 MB; dreg/sreg alias h, dead before gemm1) ----
    char* p = (char*)d_ws;
    int*   csr    = (int*)p;            p += sizeof(int) * (size_t)NHALF * CAP2;  // 7.2 MB
    int*   starts = (int*)p;            p += sizeof(int) * N;
    int*   ends   = (int*)p;            p += sizeof(int) * N;
    float* norm_s = (float*)p;          p += sizeof(float) * N;
    float* norm_d = (float*)p;          p += sizeof(float) * N;
    int*   gcur_d = (int*)p;            p += sizeof(int) * NSB;        // zeroed
    int*   gcur_s = (int*)p;            p += sizeof(int) * NSB;        // zeroed
    p = (char*)(((size_t)p + 255) & ~(size_t)255);
    __half* h     = (__half*)p;         p += sizeof(__half) * (size_t)N * 64; // 12.8 MB
    p = (char*)(((size_t)p + 255) & ~(size_t)255);
    float* x      = (float*)p;          p += sizeof(float) * (size_t)N * 64;  // 25.6 MB
    // aliases inside h (consumed by shist/csr2 before gemm1 writes h):
    int*            dreg = (int*)h;                                          // 7.06 MB
    unsigned short* sreg = (unsigned short*)((char*)h + sizeof(int) * (size_t)NSB * CAP1); // 3.5 MB

    hipMemsetAsync(gcur_d, 0, sizeof(int) * 2 * NSB, stream);

    // ---- build: partition -> src histogram -> exact CSR ----
    part_kernel<<<(E + PCHUNK - 1) / PCHUNK, 256, 0, stream>>>(edge_src, edge_dst,
                                                               gcur_d, gcur_s, dreg, sreg, E);
    shist_kernel<<<NSB, 256, 0, stream>>>(sreg, gcur_s, norm_s, N);
    csr2_kernel<<<NHALF, 256, 0, stream>>>(dreg, gcur_d, csr, starts, ends, norm_d, N);

    // ---- layer 1 ----
    gemm_norm_kernel<INF><<<(N + 63) / 64, 256, 0, stream>>>(features, norm_s, W1, h, N);
    gather_kernel<<<(N + 3) / 4, 256, 0, stream>>>(starts, ends, csr, h, norm_d, b1, x, N);

    // ---- layer 2 ----
    gemm_norm_kernel<HID><<<(N + 63) / 64, 256, 0, stream>>>(x, norm_s, W2, h, N);
    gather_kernel<<<(N + 3) / 4, 256, 0, stream>>>(starts, ends, csr, h, norm_d, b2, x, N);

    // ---- projection + softmax ----
    proj_softmax_kernel<<<(N + 255) / 256, 256, 0, stream>>>(x, Wp, bp, out, N);
}

// Round 11
// 280.902 us; speedup vs baseline: 1.4494x; 1.1044x over previous
//
#include <hip/hip_runtime.h>
#include <hip/hip_fp16.h>
#include <math.h>

// GCN: 2x GraphConv(norm='both') + projection + softmax.
// N=100000 nodes, E=1600000 edges, feats 128 -> 64 -> 64 -> 8. All fp32 I/O.
//
// R10 post-mortem: 64x64 vector gemm became LDS-issue bound (5 LDS instrs /
// 16 FMA per k; 35 cyc/wave/k * 8 waves * 128k * 3 rounds = 45 us ~ observed
// 47). R11: MFMA gemm — X,W cast to fp16 (err ~1e-3 << 2% tol), K=32 f16
// MFMA, fp32 accum. W pre-converted to transposed padded fp16 by wcvt_kernel;
// per-wave: 16 rows x 64 cols, A-frags via 2 global float4 loads, B-frags via
// aligned ds_read_b128, 16 mfma. Gather / CSR build unchanged from R10.

#define NODES   100000
#define INF     128
#define HID     64
#define NLAB    8

#define SB      512                         // nodes per super-bucket
#define NSB     ((NODES + SB - 1) / SB)     // 196
#define NHALF   ((NODES + 255) / 256)       // 391 half-buckets (256 nodes)
#define CAP1    9000                        // per-sb edge cap (mean 8192, sigma~90)
#define SCAP    9000                        // per-sb src cap
#define CAP2    4600                        // per-half edge cap (mean 4096, sigma~64)
#define PCHUNK  4096                        // edges per part WG
#define PEPT    (PCHUNK / 256)              // 16
#define SRCMASK 0x1FFFF                     // 17 bits

union H8 { int4 i4; __half2 h2[4]; };

typedef _Float16 half8 __attribute__((ext_vector_type(8)));
typedef float floatx4 __attribute__((ext_vector_type(4)));

// ---------------- partition edges by dst>>9; src vals by src>>9 ----------------

__global__ void part_kernel(const int* __restrict__ src, const int* __restrict__ dst,
                            int* __restrict__ gcur_d, int* __restrict__ gcur_s,
                            int* __restrict__ dreg, unsigned short* __restrict__ sreg, int E) {
    __shared__ int hd[NSB], hs[NSB], bd[NSB], bs[NSB];
    const int tid = threadIdx.x;
    const int e0 = blockIdx.x * PCHUNK;

    for (int i = tid; i < NSB; i += 256) { hd[i] = 0; hs[i] = 0; }
    __syncthreads();

    // phase A: LDS histograms; cache edges in registers
    int es[PEPT], ed[PEPT];
#pragma unroll
    for (int i = 0; i < PEPT; ++i) {
        int e = e0 + tid + i * 256;
        if (e < E) {
            es[i] = src[e]; ed[i] = dst[e];
            atomicAdd(&hd[ed[i] >> 9], 1);
            atomicAdd(&hs[es[i] >> 9], 1);
        } else es[i] = -1;
    }
    __syncthreads();

    // phase B: reserve contiguous runs (hot-line far atomics only: 392 addrs)
    for (int b = tid; b < NSB; b += 256) {
        int c = hd[b]; bd[b] = c ? atomicAdd(&gcur_d[b], c) : 0;
        c = hs[b];     bs[b] = c ? atomicAdd(&gcur_s[b], c) : 0;
    }
    __syncthreads();
    for (int b = tid; b < NSB; b += 256) { hd[b] = 0; hs[b] = 0; }
    __syncthreads();

    // phase C: scatter into runs (dst_local<<17 | src; src_local as ushort)
#pragma unroll
    for (int i = 0; i < PEPT; ++i) {
        if (es[i] >= 0) {
            int s = es[i], d = ed[i];
            int kb = d >> 9;
            int pos = bd[kb] + atomicAdd(&hd[kb], 1);
            if (pos < CAP1) dreg[(size_t)kb * CAP1 + pos] = ((d & (SB - 1)) << 17) | s;
            int ks = s >> 9;
            int ps = bs[ks] + atomicAdd(&hs[ks], 1);
            if (ps < SCAP) sreg[(size_t)ks * SCAP + ps] = (unsigned short)(s & (SB - 1));
        }
    }
}

// ---------------- src-degree histogram per super-bucket -> norm_s ----------------

__global__ void shist_kernel(const unsigned short* __restrict__ sreg,
                             const int* __restrict__ gcur_s,
                             float* __restrict__ norm_s, int Nn) {
    __shared__ int hist[SB];
    const int tid = threadIdx.x;
    const int sb = blockIdx.x;
    for (int i = tid; i < SB; i += 256) hist[i] = 0;
    __syncthreads();
    const int cnt = min(gcur_s[sb], SCAP);
    const unsigned short* base = sreg + (size_t)sb * SCAP;
    for (int i = tid; i < cnt; i += 256) atomicAdd(&hist[base[i]], 1);
    __syncthreads();
    for (int t = tid; t < SB; t += 256) {
        int node = sb * SB + t;
        if (node < Nn) norm_s[node] = rsqrtf(fmaxf((float)hist[t], 1.0f));
    }
}

// ---------------- per-half-bucket counting sort -> exact CSR ----------------
// WG j owns nodes [j*256, j*256+256) = half (j&1) of super-bucket (j>>1).

__global__ void csr2_kernel(const int* __restrict__ dreg, const int* __restrict__ gcur_d,
                            int* __restrict__ csr, int* __restrict__ starts,
                            int* __restrict__ ends, float* __restrict__ norm_d, int Nn) {
    __shared__ int hist[256], excl[256], cur[256];
    __shared__ int sorted[CAP2];
    __shared__ int tot_s;
    const int tid = threadIdx.x;
    const int j = blockIdx.x;
    const int sb = j >> 1, half = j & 1;
    const int cnt = min(gcur_d[sb], CAP1);
    const int* reg = dreg + (size_t)sb * CAP1;

    hist[tid] = 0;
    __syncthreads();

    for (int i = tid; i < cnt; i += 256) {
        int pe = reg[i];
        if (((pe >> 25) & 1) == half) atomicAdd(&hist[(pe >> 17) & 255], 1);
    }
    __syncthreads();

    // exclusive scan over 256 (Hillis-Steele)
    excl[tid] = hist[tid];
    __syncthreads();
    for (int off = 1; off < 256; off <<= 1) {
        int v = (tid >= off) ? excl[tid - off] : 0;
        __syncthreads();
        excl[tid] += v;
        __syncthreads();
    }
    int deg = hist[tid];
    int st = excl[tid] - deg;
    if (tid == 255) tot_s = min(excl[255], CAP2);
    int node = j * 256 + tid;
    if (node < Nn) {
        int gs = j * CAP2 + st;
        int dcl = min(deg, max(CAP2 - st, 0));
        starts[node] = gs;
        ends[node]   = gs + dcl;
        norm_d[node] = rsqrtf(fmaxf((float)deg, 1.0f));
    }
    cur[tid] = st;
    __syncthreads();

    for (int i = tid; i < cnt; i += 256) {
        int pe = reg[i];
        if (((pe >> 25) & 1) == half) {
            int pos = atomicAdd(&cur[(pe >> 17) & 255], 1);
            if (pos < CAP2) sorted[pos] = pe & SRCMASK;
        }
    }
    __syncthreads();

    const int tot = tot_s;
    for (int i = tid; i < tot; i += 256) csr[(size_t)j * CAP2 + i] = sorted[i];
}

// ---------------- W convert: fp32 [K][64] -> fp16 transposed [64][K+8] ----------------

__global__ void wcvt_kernel(const float* __restrict__ W1, const float* __restrict__ W2,
                            _Float16* __restrict__ wt1, _Float16* __restrict__ wt2) {
    const int N1 = 64 * (INF + 8);
    const int N2 = 64 * (HID + 8);
    int i = blockIdx.x * 256 + threadIdx.x;
    if (i < N1) {
        int n = i / (INF + 8), k = i % (INF + 8);
        wt1[i] = (k < INF) ? (_Float16)W1[k * 64 + n] : (_Float16)0.f;
    } else if (i < N1 + N2) {
        int j = i - N1;
        int n = j / (HID + 8), k = j % (HID + 8);
        wt2[j] = (k < HID) ? (_Float16)W2[k * 64 + n] : (_Float16)0.f;
    }
}

// ---------------- MFMA GEMM: Hh[row,:] = fp16( norm[row] * (X[row,:] @ W) ) ----------------
// Block = 64 rows (4 waves x 16). Wave: 16 rows x 64 cols via 4 col-tile
// accumulators, K in chunks of 32 (v_mfma_f32_16x16x32_f16, fp32 accum).
// A-frag: A[m=lane&15][k=quad*8+j] -> 2 global float4 loads + cvt.
// B-frag: Wt[n=16t+(lane&15)][k0..k0+7] -> aligned ds_read_b128 (KP=K+8 pad).
// D: col=lane&15, row=quad*4+reg (verified layouts, learn_hip m89/m120).

template <int K>
__global__ void gemm_mfma_kernel(const float* __restrict__ X, const float* __restrict__ norm,
                                 const _Float16* __restrict__ Wt, __half* __restrict__ Hh,
                                 int M) {
    constexpr int KP = K + 8;
    __shared__ _Float16 sWt[64 * KP];

    const int tid = threadIdx.x;
    constexpr int NI4 = 64 * KP * 2 / 16;       // int4 copies (KP mult of 8 -> exact)
    for (int i = tid; i < NI4; i += 256)
        ((int4*)sWt)[i] = ((const int4*)Wt)[i];
    __syncthreads();

    const int w = tid >> 6, lane = tid & 63;
    const int m16 = lane & 15, quad = lane >> 4;
    const int rowA = blockIdx.x * 64 + w * 16 + m16;
    const float* xrow = X + (size_t)(rowA < M ? rowA : M - 1) * K;

    floatx4 acc0 = {0.f, 0.f, 0.f, 0.f};
    floatx4 acc1 = acc0, acc2 = acc0, acc3 = acc0;

#pragma unroll
    for (int c = 0; c < K / 32; ++c) {
        const int k0 = c * 32 + quad * 8;
        float4 xa = *(const float4*)(xrow + k0);
        float4 xb = *(const float4*)(xrow + k0 + 4);
        half8 a;
        a[0] = (_Float16)xa.x; a[1] = (_Float16)xa.y;
        a[2] = (_Float16)xa.z; a[3] = (_Float16)xa.w;
        a[4] = (_Float16)xb.x; a[5] = (_Float16)xb.y;
        a[6] = (_Float16)xb.z; a[7] = (_Float16)xb.w;
        half8 b0 = *(const half8*)&sWt[(0 * 16 + m16) * KP + k0];
        half8 b1 = *(const half8*)&sWt[(1 * 16 + m16) * KP + k0];
        half8 b2 = *(const half8*)&sWt[(2 * 16 + m16) * KP + k0];
        half8 b3 = *(const half8*)&sWt[(3 * 16 + m16) * KP + k0];
        acc0 = __builtin_amdgcn_mfma_f32_16x16x32_f16(a, b0, acc0, 0, 0, 0);
        acc1 = __builtin_amdgcn_mfma_f32_16x16x32_f16(a, b1, acc1, 0, 0, 0);
        acc2 = __builtin_amdgcn_mfma_f32_16x16x32_f16(a, b2, acc2, 0, 0, 0);
        acc3 = __builtin_amdgcn_mfma_f32_16x16x32_f16(a, b3, acc3, 0, 0, 0);
    }

    const int rbase = blockIdx.x * 64 + w * 16 + quad * 4;
    floatx4 accs[4] = {acc0, acc1, acc2, acc3};
#pragma unroll
    for (int i = 0; i < 4; ++i) {
        int grow = rbase + i;
        if (grow < M) {
            float nm = norm[grow];
            __half* o = Hh + (size_t)grow * 64 + m16;
#pragma unroll
            for (int t = 0; t < 4; ++t)
                o[16 * t] = (__half)(accs[t][i] * nm);
        }
    }
}

// ---------------- pull gather (fp16 rows), MLP-widened, uniform-exec shfl ----------------

__global__ void gather_kernel(const int* __restrict__ starts, const int* __restrict__ ends,
                              const int* __restrict__ csr, const __half* __restrict__ Hh,
                              const float* __restrict__ nd, const float* __restrict__ b,
                              float* __restrict__ X, int Nn) {
    int node = blockIdx.x * 4 + (threadIdx.x >> 6);
    if (node >= Nn) return;                     // wave-uniform
    const int lane = threadIdx.x & 63;
    const int g = lane >> 3;                    // edge slot group 0..7
    const int c = lane & 7;                     // 16B col chunk

    const int start = starts[node], end = ends[node];
    float acc[8] = {0.f, 0.f, 0.f, 0.f, 0.f, 0.f, 0.f, 0.f};

    for (int base = start; base < end; base += 64) {
        int idx = base + lane;
        int pe = (idx < end) ? csr[idx] : 0;    // one coalesced load / 64 edges
        int ecount = min(end - base, 64);
        int nk = (ecount + 7) >> 3;             // wave-uniform trip count

        for (int k = 0; k < nk; k += 2) {
            int j0 = g + 8 * k;                 // <= 55
            int j1 = j0 + 8;                    // <= 63
            int s0 = __shfl(pe, j0, 64);        // full-wave exec (uniform bounds)
            int s1 = __shfl(pe, j1, 64);
            H8 v0, v1;
            if (j0 < ecount) v0.i4 = ((const int4*)(Hh + (size_t)s0 * 64))[c];
            else             v0.i4 = make_int4(0, 0, 0, 0);
            if (j1 < ecount) v1.i4 = ((const int4*)(Hh + (size_t)s1 * 64))[c];
            else             v1.i4 = make_int4(0, 0, 0, 0);
#pragma unroll
            for (int t = 0; t < 4; ++t) {
                float2 f0 = __half22float2(v0.h2[t]);
                float2 f1 = __half22float2(v1.h2[t]);
                acc[2 * t]     += f0.x + f1.x;
                acc[2 * t + 1] += f0.y + f1.y;
            }
        }
    }

    // reduce over g (lane bits 3,4,5)
#pragma unroll
    for (int m = 8; m <= 32; m <<= 1) {
#pragma unroll
        for (int k = 0; k < 8; ++k)
            acc[k] += __shfl_xor(acc[k], m, 64);
    }

    if (g == 0) {                               // lanes 0..7 write 8 cols each
        float nm = nd[node];
        float4 b0 = ((const float4*)b)[2 * c];
        float4 b1 = ((const float4*)b)[2 * c + 1];
        float4 r0, r1;
        r0.x = fmaxf(fmaf(acc[0], nm, b0.x), 0.f);
        r0.y = fmaxf(fmaf(acc[1], nm, b0.y), 0.f);
        r0.z = fmaxf(fmaf(acc[2], nm, b0.z), 0.f);
        r0.w = fmaxf(fmaf(acc[3], nm, b0.w), 0.f);
        r1.x = fmaxf(fmaf(acc[4], nm, b1.x), 0.f);
        r1.y = fmaxf(fmaf(acc[5], nm, b1.y), 0.f);
        r1.z = fmaxf(fmaf(acc[6], nm, b1.z), 0.f);
        r1.w = fmaxf(fmaf(acc[7], nm, b1.w), 0.f);
        ((float4*)(X + (size_t)node * 64))[2 * c]     = r0;
        ((float4*)(X + (size_t)node * 64))[2 * c + 1] = r1;
    }
}

// ---------------- projection (64x8) + softmax ----------------

__global__ void proj_softmax_kernel(const float* __restrict__ X, const float* __restrict__ Wp,
                                    const float* __restrict__ bp, float* __restrict__ out, int M) {
    __shared__ float sW[64 * NLAB];
    __shared__ float sb[NLAB];
    int tid = threadIdx.x;
    for (int i = tid; i < 64 * NLAB; i += 256) sW[i] = Wp[i];
    if (tid < NLAB) sb[tid] = bp[tid];
    __syncthreads();

    int row = blockIdx.x * 256 + tid;
    if (row >= M) return;

    float logit[NLAB];
#pragma unroll
    for (int l = 0; l < NLAB; ++l) logit[l] = sb[l];
    const float4* x4 = (const float4*)(X + (size_t)row * 64);
#pragma unroll 4
    for (int kk = 0; kk < 16; ++kk) {
        float4 v = x4[kk];
        const float xs[4] = {v.x, v.y, v.z, v.w};
#pragma unroll
        for (int j = 0; j < 4; ++j) {
            int k = kk * 4 + j;
            float xv = xs[j];
#pragma unroll
            for (int l = 0; l < NLAB; ++l)
                logit[l] = fmaf(xv, sW[k * NLAB + l], logit[l]);
        }
    }
    float mx = logit[0];
#pragma unroll
    for (int l = 1; l < NLAB; ++l) mx = fmaxf(mx, logit[l]);
    float s = 0.0f;
#pragma unroll
    for (int l = 0; l < NLAB; ++l) { logit[l] = __expf(logit[l] - mx); s += logit[l]; }
    float inv = 1.0f / s;
#pragma unroll
    for (int l = 0; l < NLAB; ++l) out[(size_t)row * NLAB + l] = logit[l] * inv;
}

// ---------------- launch ----------------

extern "C" void kernel_launch(void* const* d_in, const int* in_sizes, int n_in,
                              void* d_out, int out_size, void* d_ws, size_t ws_size,
                              hipStream_t stream) {
    const float* features = (const float*)d_in[0];
    const int*   edge_src = (const int*)d_in[1];
    const int*   edge_dst = (const int*)d_in[2];
    const float* W1 = (const float*)d_in[4];
    const float* b1 = (const float*)d_in[5];
    const float* W2 = (const float*)d_in[6];
    const float* b2 = (const float*)d_in[7];
    const float* Wp = (const float*)d_in[8];
    const float* bp = (const float*)d_in[9];
    float* out = (float*)d_out;

    const int N = NODES;
    const int E = in_sizes[1];

    // ---- workspace layout (~48 MB; dreg/sreg alias h, dead before gemm1) ----
    char* p = (char*)d_ws;
    int*   csr    = (int*)p;            p += sizeof(int) * (size_t)NHALF * CAP2;  // 7.2 MB
    int*   starts = (int*)p;            p += sizeof(int) * N;
    int*   ends   = (int*)p;            p += sizeof(int) * N;
    float* norm_s = (float*)p;          p += sizeof(float) * N;
    float* norm_d = (float*)p;          p += sizeof(float) * N;
    int*   gcur_d = (int*)p;            p += sizeof(int) * NSB;        // zeroed
    int*   gcur_s = (int*)p;            p += sizeof(int) * NSB;        // zeroed
    p = (char*)(((size_t)p + 255) & ~(size_t)255);
    _Float16* wt1 = (_Float16*)p;       p += sizeof(_Float16) * 64 * (INF + 8);
    _Float16* wt2 = (_Float16*)p;       p += sizeof(_Float16) * 64 * (HID + 8);
    p = (char*)(((size_t)p + 255) & ~(size_t)255);
    __half* h     = (__half*)p;         p += sizeof(__half) * (size_t)N * 64; // 12.8 MB
    p = (char*)(((size_t)p + 255) & ~(size_t)255);
    float* x      = (float*)p;          p += sizeof(float) * (size_t)N * 64;  // 25.6 MB
    // aliases inside h (consumed by shist/csr2 before gemm1 writes h):
    int*            dreg = (int*)h;                                          // 7.06 MB
    unsigned short* sreg = (unsigned short*)((char*)h + sizeof(int) * (size_t)NSB * CAP1); // 3.5 MB

    hipMemsetAsync(gcur_d, 0, sizeof(int) * 2 * NSB, stream);

    // ---- build: W convert + partition -> src histogram -> exact CSR ----
    wcvt_kernel<<<(64 * (INF + HID + 16) + 255) / 256, 256, 0, stream>>>(W1, W2, wt1, wt2);
    part_kernel<<<(E + PCHUNK - 1) / PCHUNK, 256, 0, stream>>>(edge_src, edge_dst,
                                                               gcur_d, gcur_s, dreg, sreg, E);
    shist_kernel<<<NSB, 256, 0, stream>>>(sreg, gcur_s, norm_s, N);
    csr2_kernel<<<NHALF, 256, 0, stream>>>(dreg, gcur_d, csr, starts, ends, norm_d, N);

    // ---- layer 1 ----
    gemm_mfma_kernel<INF><<<(N + 63) / 64, 256, 0, stream>>>(features, norm_s, wt1, h, N);
    gather_kernel<<<(N + 3) / 4, 256, 0, stream>>>(starts, ends, csr, h, norm_d, b1, x, N);

    // ---- layer 2 ----
    gemm_mfma_kernel<HID><<<(N + 63) / 64, 256, 0, stream>>>(x, norm_s, wt2, h, N);
    gather_kernel<<<(N + 3) / 4, 256, 0, stream>>>(starts, ends, csr, h, norm_d, b2, x, N);

    // ---- projection + softmax ----
    proj_softmax_kernel<<<(N + 255) / 256, 256, 0, stream>>>(x, Wp, bp, out, N);
}

// Round 12
// 279.450 us; speedup vs baseline: 1.4570x; 1.0052x over previous
//
#include <hip/hip_runtime.h>
#include <hip/hip_fp16.h>
#include <math.h>

// GCN: 2x GraphConv(norm='both') + projection + softmax.
// N=100000 nodes, E=1600000 edges, feats 128 -> 64 -> 64 -> 8. All fp32 I/O.
//
// R11 post-mortem: gather flipped to VALU-issue bound (60% VALUBusy, 2.0 TB/s
// < 2.8 random-line ceiling): 16 cvt + 16 add per 2 edges. R12: pair-combine
// in fp16 (v_pk_add_f16, 4 instr / 16 values) before fp32 accumulate; layer
// activations X stored fp16 (halves gather writes, gemm2 A-fetch + its cvts,
// proj reads). MFMA gemm (R11) and CSR build (R6) otherwise unchanged.

#define NODES   100000
#define INF     128
#define HID     64
#define NLAB    8

#define SB      512                         // nodes per super-bucket
#define NSB     ((NODES + SB - 1) / SB)     // 196
#define NHALF   ((NODES + 255) / 256)       // 391 half-buckets (256 nodes)
#define CAP1    9000                        // per-sb edge cap (mean 8192, sigma~90)
#define SCAP    9000                        // per-sb src cap
#define CAP2    4600                        // per-half edge cap (mean 4096, sigma~64)
#define PCHUNK  4096                        // edges per part WG
#define PEPT    (PCHUNK / 256)              // 16
#define SRCMASK 0x1FFFF                     // 17 bits

union H8 { int4 i4; __half2 h2[4]; };

typedef _Float16 half8 __attribute__((ext_vector_type(8)));
typedef float floatx4 __attribute__((ext_vector_type(4)));

// ---------------- partition edges by dst>>9; src vals by src>>9 ----------------

__global__ void part_kernel(const int* __restrict__ src, const int* __restrict__ dst,
                            int* __restrict__ gcur_d, int* __restrict__ gcur_s,
                            int* __restrict__ dreg, unsigned short* __restrict__ sreg, int E) {
    __shared__ int hd[NSB], hs[NSB], bd[NSB], bs[NSB];
    const int tid = threadIdx.x;
    const int e0 = blockIdx.x * PCHUNK;

    for (int i = tid; i < NSB; i += 256) { hd[i] = 0; hs[i] = 0; }
    __syncthreads();

    // phase A: LDS histograms; cache edges in registers
    int es[PEPT], ed[PEPT];
#pragma unroll
    for (int i = 0; i < PEPT; ++i) {
        int e = e0 + tid + i * 256;
        if (e < E) {
            es[i] = src[e]; ed[i] = dst[e];
            atomicAdd(&hd[ed[i] >> 9], 1);
            atomicAdd(&hs[es[i] >> 9], 1);
        } else es[i] = -1;
    }
    __syncthreads();

    // phase B: reserve contiguous runs (hot-line far atomics only: 392 addrs)
    for (int b = tid; b < NSB; b += 256) {
        int c = hd[b]; bd[b] = c ? atomicAdd(&gcur_d[b], c) : 0;
        c = hs[b];     bs[b] = c ? atomicAdd(&gcur_s[b], c) : 0;
    }
    __syncthreads();
    for (int b = tid; b < NSB; b += 256) { hd[b] = 0; hs[b] = 0; }
    __syncthreads();

    // phase C: scatter into runs (dst_local<<17 | src; src_local as ushort)
#pragma unroll
    for (int i = 0; i < PEPT; ++i) {
        if (es[i] >= 0) {
            int s = es[i], d = ed[i];
            int kb = d >> 9;
            int pos = bd[kb] + atomicAdd(&hd[kb], 1);
            if (pos < CAP1) dreg[(size_t)kb * CAP1 + pos] = ((d & (SB - 1)) << 17) | s;
            int ks = s >> 9;
            int ps = bs[ks] + atomicAdd(&hs[ks], 1);
            if (ps < SCAP) sreg[(size_t)ks * SCAP + ps] = (unsigned short)(s & (SB - 1));
        }
    }
}

// ---------------- src-degree histogram per super-bucket -> norm_s ----------------

__global__ void shist_kernel(const unsigned short* __restrict__ sreg,
                             const int* __restrict__ gcur_s,
                             float* __restrict__ norm_s, int Nn) {
    __shared__ int hist[SB];
    const int tid = threadIdx.x;
    const int sb = blockIdx.x;
    for (int i = tid; i < SB; i += 256) hist[i] = 0;
    __syncthreads();
    const int cnt = min(gcur_s[sb], SCAP);
    const unsigned short* base = sreg + (size_t)sb * SCAP;
    for (int i = tid; i < cnt; i += 256) atomicAdd(&hist[base[i]], 1);
    __syncthreads();
    for (int t = tid; t < SB; t += 256) {
        int node = sb * SB + t;
        if (node < Nn) norm_s[node] = rsqrtf(fmaxf((float)hist[t], 1.0f));
    }
}

// ---------------- per-half-bucket counting sort -> exact CSR ----------------
// WG j owns nodes [j*256, j*256+256) = half (j&1) of super-bucket (j>>1).

__global__ void csr2_kernel(const int* __restrict__ dreg, const int* __restrict__ gcur_d,
                            int* __restrict__ csr, int* __restrict__ starts,
                            int* __restrict__ ends, float* __restrict__ norm_d, int Nn) {
    __shared__ int hist[256], excl[256], cur[256];
    __shared__ int sorted[CAP2];
    __shared__ int tot_s;
    const int tid = threadIdx.x;
    const int j = blockIdx.x;
    const int sb = j >> 1, half = j & 1;
    const int cnt = min(gcur_d[sb], CAP1);
    const int* reg = dreg + (size_t)sb * CAP1;

    hist[tid] = 0;
    __syncthreads();

    for (int i = tid; i < cnt; i += 256) {
        int pe = reg[i];
        if (((pe >> 25) & 1) == half) atomicAdd(&hist[(pe >> 17) & 255], 1);
    }
    __syncthreads();

    // exclusive scan over 256 (Hillis-Steele)
    excl[tid] = hist[tid];
    __syncthreads();
    for (int off = 1; off < 256; off <<= 1) {
        int v = (tid >= off) ? excl[tid - off] : 0;
        __syncthreads();
        excl[tid] += v;
        __syncthreads();
    }
    int deg = hist[tid];
    int st = excl[tid] - deg;
    if (tid == 255) tot_s = min(excl[255], CAP2);
    int node = j * 256 + tid;
    if (node < Nn) {
        int gs = j * CAP2 + st;
        int dcl = min(deg, max(CAP2 - st, 0));
        starts[node] = gs;
        ends[node]   = gs + dcl;
        norm_d[node] = rsqrtf(fmaxf((float)deg, 1.0f));
    }
    cur[tid] = st;
    __syncthreads();

    for (int i = tid; i < cnt; i += 256) {
        int pe = reg[i];
        if (((pe >> 25) & 1) == half) {
            int pos = atomicAdd(&cur[(pe >> 17) & 255], 1);
            if (pos < CAP2) sorted[pos] = pe & SRCMASK;
        }
    }
    __syncthreads();

    const int tot = tot_s;
    for (int i = tid; i < tot; i += 256) csr[(size_t)j * CAP2 + i] = sorted[i];
}

// ---------------- W convert: fp32 [K][64] -> fp16 transposed [64][K+8] ----------------

__global__ void wcvt_kernel(const float* __restrict__ W1, const float* __restrict__ W2,
                            _Float16* __restrict__ wt1, _Float16* __restrict__ wt2) {
    const int N1 = 64 * (INF + 8);
    const int N2 = 64 * (HID + 8);
    int i = blockIdx.x * 256 + threadIdx.x;
    if (i < N1) {
        int n = i / (INF + 8), k = i % (INF + 8);
        wt1[i] = (k < INF) ? (_Float16)W1[k * 64 + n] : (_Float16)0.f;
    } else if (i < N1 + N2) {
        int j = i - N1;
        int n = j / (HID + 8), k = j % (HID + 8);
        wt2[j] = (k < HID) ? (_Float16)W2[k * 64 + n] : (_Float16)0.f;
    }
}

// ---------------- MFMA GEMM: Hh[row,:] = fp16( norm[row] * (X[row,:] @ W) ) ----------------
// Block = 64 rows (4 waves x 16). Wave: 16 rows x 64 cols via 4 col-tile
// accumulators, K in chunks of 32 (v_mfma_f32_16x16x32_f16, fp32 accum).
// A-frag: A[m=lane&15][k=quad*8+j]; fp32 input -> 2 float4 loads + cvt,
// fp16 input -> one 16B half8 load. B-frag: aligned ds_read_b128 (KP pad).
// D: col=lane&15, row=quad*4+reg (verified layouts, learn_hip m89/m120).

template <int K, bool IN16>
__global__ void gemm_mfma_kernel(const void* __restrict__ Xv, const float* __restrict__ norm,
                                 const _Float16* __restrict__ Wt, __half* __restrict__ Hh,
                                 int M) {
    constexpr int KP = K + 8;
    __shared__ _Float16 sWt[64 * KP];

    const int tid = threadIdx.x;
    constexpr int NI4 = 64 * KP * 2 / 16;       // int4 copies (KP mult of 8 -> exact)
    for (int i = tid; i < NI4; i += 256)
        ((int4*)sWt)[i] = ((const int4*)Wt)[i];
    __syncthreads();

    const int w = tid >> 6, lane = tid & 63;
    const int m16 = lane & 15, quad = lane >> 4;
    const int rowA = blockIdx.x * 64 + w * 16 + m16;
    const int rowC = (rowA < M) ? rowA : (M - 1);

    floatx4 acc0 = {0.f, 0.f, 0.f, 0.f};
    floatx4 acc1 = acc0, acc2 = acc0, acc3 = acc0;

#pragma unroll
    for (int c = 0; c < K / 32; ++c) {
        const int k0 = c * 32 + quad * 8;
        half8 a;
        if constexpr (IN16) {
            const _Float16* xrow = (const _Float16*)Xv + (size_t)rowC * K;
            a = *(const half8*)(xrow + k0);
        } else {
            const float* xrow = (const float*)Xv + (size_t)rowC * K;
            float4 xa = *(const float4*)(xrow + k0);
            float4 xb = *(const float4*)(xrow + k0 + 4);
            a[0] = (_Float16)xa.x; a[1] = (_Float16)xa.y;
            a[2] = (_Float16)xa.z; a[3] = (_Float16)xa.w;
            a[4] = (_Float16)xb.x; a[5] = (_Float16)xb.y;
            a[6] = (_Float16)xb.z; a[7] = (_Float16)xb.w;
        }
        half8 b0 = *(const half8*)&sWt[(0 * 16 + m16) * KP + k0];
        half8 b1 = *(const half8*)&sWt[(1 * 16 + m16) * KP + k0];
        half8 b2 = *(const half8*)&sWt[(2 * 16 + m16) * KP + k0];
        half8 b3 = *(const half8*)&sWt[(3 * 16 + m16) * KP + k0];
        acc0 = __builtin_amdgcn_mfma_f32_16x16x32_f16(a, b0, acc0, 0, 0, 0);
        acc1 = __builtin_amdgcn_mfma_f32_16x16x32_f16(a, b1, acc1, 0, 0, 0);
        acc2 = __builtin_amdgcn_mfma_f32_16x16x32_f16(a, b2, acc2, 0, 0, 0);
        acc3 = __builtin_amdgcn_mfma_f32_16x16x32_f16(a, b3, acc3, 0, 0, 0);
    }

    const int rbase = blockIdx.x * 64 + w * 16 + quad * 4;
    floatx4 accs[4] = {acc0, acc1, acc2, acc3};
#pragma unroll
    for (int i = 0; i < 4; ++i) {
        int grow = rbase + i;
        if (grow < M) {
            float nm = norm[grow];
            __half* o = Hh + (size_t)grow * 64 + m16;
#pragma unroll
            for (int t = 0; t < 4; ++t)
                o[16 * t] = (__half)(accs[t][i] * nm);
        }
    }
}

// ---------------- pull gather (fp16 rows), pk_f16 pair-combine ----------------
// One wave per node. Coalesced csr prefetch; group g handles edge slots
// j = g+8k (wave-uniform bounds, full-exec shfl); lane c reads int4 = 8 fp16
// cols. Two edges' rows pair-added with v_pk_add_f16 (4 instr / 16 vals),
// then converted + accumulated fp32. Output X written fp16 (int4 per lane).

__global__ void gather_kernel(const int* __restrict__ starts, const int* __restrict__ ends,
                              const int* __restrict__ csr, const __half* __restrict__ Hh,
                              const float* __restrict__ nd, const float* __restrict__ b,
                              __half* __restrict__ Xh, int Nn) {
    int node = blockIdx.x * 4 + (threadIdx.x >> 6);
    if (node >= Nn) return;                     // wave-uniform
    const int lane = threadIdx.x & 63;
    const int g = lane >> 3;                    // edge slot group 0..7
    const int c = lane & 7;                     // 16B col chunk

    const int start = starts[node], end = ends[node];
    float acc[8] = {0.f, 0.f, 0.f, 0.f, 0.f, 0.f, 0.f, 0.f};

    for (int base = start; base < end; base += 64) {
        int idx = base + lane;
        int pe = (idx < end) ? csr[idx] : 0;    // one coalesced load / 64 edges
        int ecount = min(end - base, 64);
        int nk = (ecount + 7) >> 3;             // wave-uniform trip count

        for (int k = 0; k < nk; k += 2) {
            int j0 = g + 8 * k;                 // <= 55
            int j1 = j0 + 8;                    // <= 63
            int s0 = __shfl(pe, j0, 64);        // full-wave exec (uniform bounds)
            int s1 = __shfl(pe, j1, 64);
            H8 v0, v1;
            if (j0 < ecount) v0.i4 = ((const int4*)(Hh + (size_t)s0 * 64))[c];
            else             v0.i4 = make_int4(0, 0, 0, 0);
            if (j1 < ecount) v1.i4 = ((const int4*)(Hh + (size_t)s1 * 64))[c];
            else             v1.i4 = make_int4(0, 0, 0, 0);
#pragma unroll
            for (int t = 0; t < 4; ++t) {
                __half2 s = __hadd2(v0.h2[t], v1.h2[t]);   // v_pk_add_f16
                float2 f = __half22float2(s);
                acc[2 * t]     += f.x;
                acc[2 * t + 1] += f.y;
            }
        }
    }

    // reduce over g (lane bits 3,4,5)
#pragma unroll
    for (int m = 8; m <= 32; m <<= 1) {
#pragma unroll
        for (int k = 0; k < 8; ++k)
            acc[k] += __shfl_xor(acc[k], m, 64);
    }

    if (g == 0) {                               // lanes 0..7 write 8 cols each
        float nm = nd[node];
        float4 b0 = ((const float4*)b)[2 * c];
        float4 b1 = ((const float4*)b)[2 * c + 1];
        H8 o;
        o.h2[0] = __floats2half2_rn(fmaxf(fmaf(acc[0], nm, b0.x), 0.f),
                                    fmaxf(fmaf(acc[1], nm, b0.y), 0.f));
        o.h2[1] = __floats2half2_rn(fmaxf(fmaf(acc[2], nm, b0.z), 0.f),
                                    fmaxf(fmaf(acc[3], nm, b0.w), 0.f));
        o.h2[2] = __floats2half2_rn(fmaxf(fmaf(acc[4], nm, b1.x), 0.f),
                                    fmaxf(fmaf(acc[5], nm, b1.y), 0.f));
        o.h2[3] = __floats2half2_rn(fmaxf(fmaf(acc[6], nm, b1.z), 0.f),
                                    fmaxf(fmaf(acc[7], nm, b1.w), 0.f));
        ((int4*)(Xh + (size_t)node * 64))[c] = o.i4;
    }
}

// ---------------- projection (64x8) + softmax, fp16 input ----------------

__global__ void proj_softmax_kernel(const __half* __restrict__ Xh, const float* __restrict__ Wp,
                                    const float* __restrict__ bp, float* __restrict__ out, int M) {
    __shared__ float sW[64 * NLAB];
    __shared__ float sb[NLAB];
    int tid = threadIdx.x;
    for (int i = tid; i < 64 * NLAB; i += 256) sW[i] = Wp[i];
    if (tid < NLAB) sb[tid] = bp[tid];
    __syncthreads();

    int row = blockIdx.x * 256 + tid;
    if (row >= M) return;

    float logit[NLAB];
#pragma unroll
    for (int l = 0; l < NLAB; ++l) logit[l] = sb[l];
    const H8* x8 = (const H8*)(Xh + (size_t)row * 64);
#pragma unroll 2
    for (int kk = 0; kk < 8; ++kk) {
        H8 v = x8[kk];
#pragma unroll
        for (int t = 0; t < 4; ++t) {
            float2 f = __half22float2(v.h2[t]);
            int k = kk * 8 + 2 * t;
#pragma unroll
            for (int l = 0; l < NLAB; ++l)
                logit[l] = fmaf(f.x, sW[k * NLAB + l], logit[l]);
#pragma unroll
            for (int l = 0; l < NLAB; ++l)
                logit[l] = fmaf(f.y, sW[(k + 1) * NLAB + l], logit[l]);
        }
    }
    float mx = logit[0];
#pragma unroll
    for (int l = 1; l < NLAB; ++l) mx = fmaxf(mx, logit[l]);
    float s = 0.0f;
#pragma unroll
    for (int l = 0; l < NLAB; ++l) { logit[l] = __expf(logit[l] - mx); s += logit[l]; }
    float inv = 1.0f / s;
#pragma unroll
    for (int l = 0; l < NLAB; ++l) out[(size_t)row * NLAB + l] = logit[l] * inv;
}

// ---------------- launch ----------------

extern "C" void kernel_launch(void* const* d_in, const int* in_sizes, int n_in,
                              void* d_out, int out_size, void* d_ws, size_t ws_size,
                              hipStream_t stream) {
    const float* features = (const float*)d_in[0];
    const int*   edge_src = (const int*)d_in[1];
    const int*   edge_dst = (const int*)d_in[2];
    const float* W1 = (const float*)d_in[4];
    const float* b1 = (const float*)d_in[5];
    const float* W2 = (const float*)d_in[6];
    const float* b2 = (const float*)d_in[7];
    const float* Wp = (const float*)d_in[8];
    const float* bp = (const float*)d_in[9];
    float* out = (float*)d_out;

    const int N = NODES;
    const int E = in_sizes[1];

    // ---- workspace layout (~35 MB; dreg/sreg alias h, dead before gemm1) ----
    char* p = (char*)d_ws;
    int*   csr    = (int*)p;            p += sizeof(int) * (size_t)NHALF * CAP2;  // 7.2 MB
    int*   starts = (int*)p;            p += sizeof(int) * N;
    int*   ends   = (int*)p;            p += sizeof(int) * N;
    float* norm_s = (float*)p;          p += sizeof(float) * N;
    float* norm_d = (float*)p;          p += sizeof(float) * N;
    int*   gcur_d = (int*)p;            p += sizeof(int) * NSB;        // zeroed
    int*   gcur_s = (int*)p;            p += sizeof(int) * NSB;        // zeroed
    p = (char*)(((size_t)p + 255) & ~(size_t)255);
    _Float16* wt1 = (_Float16*)p;       p += sizeof(_Float16) * 64 * (INF + 8);
    _Float16* wt2 = (_Float16*)p;       p += sizeof(_Float16) * 64 * (HID + 8);
    p = (char*)(((size_t)p + 255) & ~(size_t)255);
    __half* h     = (__half*)p;         p += sizeof(__half) * (size_t)N * 64; // 12.8 MB
    p = (char*)(((size_t)p + 255) & ~(size_t)255);
    __half* x     = (__half*)p;         p += sizeof(__half) * (size_t)N * 64; // 12.8 MB
    // aliases inside h (consumed by shist/csr2 before gemm1 writes h):
    int*            dreg = (int*)h;                                          // 7.06 MB
    unsigned short* sreg = (unsigned short*)((char*)h + sizeof(int) * (size_t)NSB * CAP1); // 3.5 MB

    hipMemsetAsync(gcur_d, 0, sizeof(int) * 2 * NSB, stream);

    // ---- build: W convert + partition -> src histogram -> exact CSR ----
    wcvt_kernel<<<(64 * (INF + HID + 16) + 255) / 256, 256, 0, stream>>>(W1, W2, wt1, wt2);
    part_kernel<<<(E + PCHUNK - 1) / PCHUNK, 256, 0, stream>>>(edge_src, edge_dst,
                                                               gcur_d, gcur_s, dreg, sreg, E);
    shist_kernel<<<NSB, 256, 0, stream>>>(sreg, gcur_s, norm_s, N);
    csr2_kernel<<<NHALF, 256, 0, stream>>>(dreg, gcur_d, csr, starts, ends, norm_d, N);

    // ---- layer 1 ----
    gemm_mfma_kernel<INF, false><<<(N + 63) / 64, 256, 0, stream>>>(features, norm_s, wt1, h, N);
    gather_kernel<<<(N + 3) / 4, 256, 0, stream>>>(starts, ends, csr, h, norm_d, b1, x, N);

    // ---- layer 2 ----
    gemm_mfma_kernel<HID, true><<<(N + 63) / 64, 256, 0, stream>>>(x, norm_s, wt2, h, N);
    gather_kernel<<<(N + 3) / 4, 256, 0, stream>>>(starts, ends, csr, h, norm_d, b2, x, N);

    // ---- projection + softmax ----
    proj_softmax_kernel<<<(N + 255) / 256, 256, 0, stream>>>(x, Wp, bp, out, N);
}